// Round 1
// baseline (452.886 us; speedup 1.0000x reference)
//
#include <hip/hip_runtime.h>
#include <math.h>

#define N_NODES 20000
#define N_EDGES 50000
#define HID 128
#define OUT_DIM 64
#define N_SLOTS 256   // N_PAIRS * 2 flattened targets
#define N_PAIRS 128
#define CAP 2048      // max incident edges stored per target slot

// ---------- helpers ----------
__device__ __forceinline__ float dot128(const float* __restrict__ w,
                                        const float* __restrict__ xs) {
    const float4* w4 = (const float4*)w;
    const float4* x4 = (const float4*)xs;
    float acc = 0.f;
#pragma unroll
    for (int k = 0; k < 32; ++k) {
        float4 a = w4[k];
        float4 b = x4[k];
        acc += a.x * b.x + a.y * b.y + a.z * b.z + a.w * b.w;
    }
    return acc;
}

// ---------- kernels ----------
__global__ void k_zero(int* __restrict__ cnt) {
    cnt[threadIdx.x] = 0;
}

// x0[n][j] = in_b[j] + sum_k in_W[j][k] * nf[n][k]   (8 nodes per block, 128 threads)
__global__ __launch_bounds__(128) void k_in_proj(const float* __restrict__ nf,
                                                 const float* __restrict__ W,
                                                 const float* __restrict__ b,
                                                 float* __restrict__ x) {
    __shared__ __align__(16) float xs[8 * 128];
    const int n0 = blockIdx.x * 8;
    const int j = threadIdx.x;
    for (int idx = j; idx < 8 * 128; idx += 128) xs[idx] = nf[n0 * 128 + idx];
    __syncthreads();
    float acc[8];
#pragma unroll
    for (int i = 0; i < 8; ++i) acc[i] = 0.f;
    const float4* w4 = (const float4*)(W + j * 128);
#pragma unroll 4
    for (int k = 0; k < 32; ++k) {
        float4 w = w4[k];
#pragma unroll
        for (int i = 0; i < 8; ++i) {
            float4 xv = ((const float4*)(xs + i * 128))[k];
            acc[i] += w.x * xv.x + w.y * xv.y + w.z * xv.z + w.w * xv.w;
        }
    }
    float bb = b[j];
#pragma unroll
    for (int i = 0; i < 8; ++i) x[(n0 + i) * 128 + j] = acc[i] + bb;
}

// build per-slot incident edge lists: one block per target slot scans all edges
__global__ void k_prep(const int* __restrict__ ei, const int* __restrict__ tp,
                       int* __restrict__ cnt, int2* __restrict__ lst) {
    const int slot = blockIdx.x;
    const int u = tp[slot];
    const int* src = ei;
    const int* dst = ei + N_EDGES;
    for (int e = threadIdx.x; e < N_EDGES; e += blockDim.x) {
        int s = src[e];
        int d = dst[e];
        if (s == u || d == u) {
            int nbr = (s == u) ? d : s;   // reference: if src==target, nbr=dst, else src
            int pos = atomicAdd(&cnt[slot], 1);
            if (pos < CAP) lst[slot * CAP + pos] = make_int2(e, nbr);
        }
    }
}

// Per-target fused attention layer. One block (128 threads) per target slot.
// agg[slot] = op_W @ (has_nbr ? attn_out : tf_u) + op_b     (NOT relu'd here)
__global__ __launch_bounds__(128) void k_attn(
    const float* __restrict__ x, const float* __restrict__ ts,
    const int* __restrict__ tp, const int* __restrict__ cnt,
    const int2* __restrict__ lst,
    const float* __restrict__ ftW, const float* __restrict__ ftb,
    const float* __restrict__ teW1, const float* __restrict__ teb1,
    const float* __restrict__ teW2, const float* __restrict__ teb2,
    const float* __restrict__ aiW, const float* __restrict__ aib,
    const float* __restrict__ aoW, const float* __restrict__ aob,
    const float* __restrict__ opW, const float* __restrict__ opb,
    float* __restrict__ agg) {
    __shared__ __align__(16) float xu[128], tfu[128], xn[128], t1[128], z[128],
        prod[128], outv[128];
    __shared__ float mh[4], lh[4], ch[4], wh[4];

    const int slot = blockIdx.x;
    const int u = tp[slot];
    const int j = threadIdx.x;
    const int head = j >> 5;
    const float scale = 0.17677669529663687f;  // 1/sqrt(32)

    const float* Wq = aiW;
    const float* Wk = aiW + 128 * 128;
    const float* Wv = aiW + 256 * 128;
    const float* bq = aib;
    const float* bk = aib + 128;
    const float* bv = aib + 256;

    xu[j] = x[u * 128 + j];
    if (j < 4) { mh[j] = -INFINITY; lh[j] = 0.f; }
    __syncthreads();
    tfu[j] = ftb[j] + dot128(ftW + j * 128, xu);
    __syncthreads();
    const float qj = bq[j] + dot128(Wq + j * 128, tfu);
    float oj = 0.f;

    const int count = min(cnt[slot], CAP);
    for (int i = 0; i < count; ++i) {
        int2 en = lst[slot * CAP + i];
        const int e = en.x;
        const int nbr = en.y;
        const float tse = ts[e];
        xn[j] = x[nbr * 128 + j];
        t1[j] = fmaxf(tse * teW1[j] + teb1[j], 0.f);
        __syncthreads();
        // z = tf[nbr] + tfeat_e
        z[j] = teb2[j] + dot128(teW2 + j * 128, t1) + ftb[j] +
               dot128(ftW + j * 128, xn);
        __syncthreads();
        const float kk = bk[j] + dot128(Wk + j * 128, z);
        const float vv = bv[j] + dot128(Wv + j * 128, z);
        prod[j] = qj * kk;
        __syncthreads();
        if (j < 4) {
            float s = 0.f;
#pragma unroll
            for (int t = 0; t < 32; ++t) s += prod[j * 32 + t];
            s *= scale;
            float m_old = mh[j];
            float m_new = fmaxf(m_old, s);
            float c = __expf(m_old - m_new);   // exp(-inf)=0 on first edge
            float w = __expf(s - m_new);
            mh[j] = m_new;
            lh[j] = lh[j] * c + w;
            ch[j] = c;
            wh[j] = w;
        }
        __syncthreads();
        oj = oj * ch[head] + wh[head] * vv;
        // next iter's LDS writes are separated from this iter's reads by the
        // t1/z/prod barriers above, so no trailing barrier needed
    }

    if (count > 0) {
        outv[j] = oj / lh[head];
        __syncthreads();
        float attn_j = aob[j] + dot128(aoW + j * 128, outv);
        z[j] = attn_j;
    } else {
        z[j] = tfu[j];
    }
    __syncthreads();
    agg[slot * 128 + j] = opb[j] + dot128(opW + j * 128, z);
}

__global__ void k_relu(float* __restrict__ x, int n) {
    int i = blockIdx.x * blockDim.x + threadIdx.x;
    if (i < n) x[i] = fmaxf(x[i], 0.f);
}

__global__ void k_scatter(float* __restrict__ x, const float* __restrict__ agg,
                          const int* __restrict__ tp) {
    const int slot = blockIdx.x;
    const int j = threadIdx.x;
    const int u = tp[slot];
    x[u * 128 + j] = fmaxf(agg[slot * 128 + j], 0.f);  // duplicates write identical values
}

// emb only at target slots: emb = relu(relu(agg2) @ out1.T + b1) @ out2.T + b2
__global__ __launch_bounds__(128) void k_emb(const float* __restrict__ agg,
                                             const float* __restrict__ o1W,
                                             const float* __restrict__ o1b,
                                             const float* __restrict__ o2W,
                                             const float* __restrict__ o2b,
                                             float* __restrict__ emb) {
    __shared__ __align__(16) float xt[128], e1[128];
    const int slot = blockIdx.x;
    const int j = threadIdx.x;
    xt[j] = fmaxf(agg[slot * 128 + j], 0.f);
    __syncthreads();
    e1[j] = fmaxf(o1b[j] + dot128(o1W + j * 128, xt), 0.f);
    __syncthreads();
    if (j < 64) emb[slot * 64 + j] = o2b[j] + dot128(o2W + j * 128, e1);
}

__global__ __launch_bounds__(128) void k_pair(const float* __restrict__ emb,
                                              const float* __restrict__ l1W,
                                              const float* __restrict__ l1b,
                                              const float* __restrict__ l2W,
                                              const float* __restrict__ l2b,
                                              const float* __restrict__ l3W,
                                              const float* __restrict__ l3b,
                                              float* __restrict__ out) {
    __shared__ __align__(16) float pv[128], z1[128], z2s[64];
    const int p = blockIdx.x;
    const int j = threadIdx.x;
    pv[j] = (j < 64) ? emb[(2 * p) * 64 + j] : emb[(2 * p + 1) * 64 + (j - 64)];
    __syncthreads();
    z1[j] = fmaxf(l1b[j] + dot128(l1W + j * 128, pv), 0.f);
    __syncthreads();
    if (j < 64) z2s[j] = fmaxf(l2b[j] + dot128(l2W + j * 128, z1), 0.f);
    __syncthreads();
    if (j == 0) {
        float s = l3b[0];
#pragma unroll
        for (int k = 0; k < 64; ++k) s += l3W[k] * z2s[k];
        out[p] = 1.f / (1.f + __expf(-s));
    }
}

// ---------- launch ----------
extern "C" void kernel_launch(void* const* d_in, const int* in_sizes, int n_in,
                              void* d_out, int out_size, void* d_ws, size_t ws_size,
                              hipStream_t stream) {
    const float* nf  = (const float*)d_in[0];
    const int*   ei  = (const int*)d_in[1];
    const float* ts  = (const float*)d_in[2];
    const int*   tp  = (const int*)d_in[3];
    const float* inW = (const float*)d_in[4];
    const float* inb = (const float*)d_in[5];
    const float* teW1 = (const float*)d_in[6];
    const float* teb1 = (const float*)d_in[7];
    const float* teW2 = (const float*)d_in[8];
    const float* teb2 = (const float*)d_in[9];
    const float* aiW = (const float*)d_in[10];
    const float* aib = (const float*)d_in[11];
    const float* aoW = (const float*)d_in[12];
    const float* aob = (const float*)d_in[13];
    const float* ftW = (const float*)d_in[14];
    const float* ftb = (const float*)d_in[15];
    const float* opW = (const float*)d_in[16];
    const float* opb = (const float*)d_in[17];
    const float* o1W = (const float*)d_in[18];
    const float* o1b = (const float*)d_in[19];
    const float* o2W = (const float*)d_in[20];
    const float* o2b = (const float*)d_in[21];
    const float* l1W = (const float*)d_in[22];
    const float* l1b = (const float*)d_in[23];
    const float* l2W = (const float*)d_in[24];
    const float* l2b = (const float*)d_in[25];
    const float* l3W = (const float*)d_in[26];
    const float* l3b = (const float*)d_in[27];
    float* out = (float*)d_out;

    char* ws = (char*)d_ws;
    float* x   = (float*)(ws);                         // 20000*128*4 = 10,240,000
    float* agg = (float*)(ws + 10240000);              // 256*128*4   =    131,072
    float* emb = (float*)(ws + 10371072);              // 256*64*4    =     65,536
    int*   cnt = (int*)  (ws + 10436608);              // 256*4       =      1,024
    int2*  lst = (int2*) (ws + 10437632);              // 256*CAP*8   =  4,194,304

    k_zero<<<1, N_SLOTS, 0, stream>>>(cnt);
    k_in_proj<<<N_NODES / 8, 128, 0, stream>>>(nf, inW, inb, x);
    k_prep<<<N_SLOTS, 256, 0, stream>>>(ei, tp, cnt, lst);

    for (int l = 0; l < 2; ++l) {
        k_attn<<<N_SLOTS, 128, 0, stream>>>(
            x, ts, tp, cnt, lst,
            ftW + l * 16384, ftb + l * 128,
            teW1 + l * 128, teb1 + l * 128,
            teW2 + l * 16384, teb2 + l * 128,
            aiW + l * 49152, aib + l * 384,
            aoW + l * 16384, aob + l * 128,
            opW + l * 16384, opb + l * 128, agg);
        if (l == 0) {
            k_relu<<<(N_NODES * 128) / 256, 256, 0, stream>>>(x, N_NODES * 128);
            k_scatter<<<N_SLOTS, 128, 0, stream>>>(x, agg, tp);
        }
    }
    // x2 is only ever read at target slots -> fold relu(agg2) into the emb head
    k_emb<<<N_SLOTS, 128, 0, stream>>>(agg, o1W, o1b, o2W, o2b, emb);
    k_pair<<<N_PAIRS, 128, 0, stream>>>(emb, l1W, l1b, l2W, l2b, l3W, l3b, out);
}

// Round 2
// 445.391 us; speedup vs baseline: 1.0168x; 1.0168x over previous
//
#include <hip/hip_runtime.h>
#include <math.h>

#define N_NODES 20000
#define N_EDGES 50000
#define HID 128
#define OUT_DIM 64
#define N_SLOTS 256   // N_PAIRS * 2 flattened targets
#define N_PAIRS 128
#define CAP 64        // max incident edges stored per target slot (deg ~ Poisson(5))
#define EDGE_SPLIT 16 // gridDim.y of k_edge

// ---------- helpers ----------
__device__ __forceinline__ float dot128(const float* __restrict__ w,
                                        const float* __restrict__ xs) {
    const float4* w4 = (const float4*)w;
    const float4* x4 = (const float4*)xs;
    float acc = 0.f;
#pragma unroll
    for (int k = 0; k < 32; ++k) {
        float4 a = w4[k];
        float4 b = x4[k];
        acc += a.x * b.x + a.y * b.y + a.z * b.z + a.w * b.w;
    }
    return acc;
}

// ---------- kernels ----------

// x0[n][j] = in_b[j] + sum_k in_W[j][k] * nf[n][k]   (8 nodes per block, 128 threads)
__global__ __launch_bounds__(128) void k_in_proj(const float* __restrict__ nf,
                                                 const float* __restrict__ W,
                                                 const float* __restrict__ b,
                                                 float* __restrict__ x) {
    __shared__ __align__(16) float xs[8 * 128];
    const int n0 = blockIdx.x * 8;
    const int j = threadIdx.x;
    for (int idx = j; idx < 8 * 128; idx += 128) xs[idx] = nf[n0 * 128 + idx];
    __syncthreads();
    float acc[8];
#pragma unroll
    for (int i = 0; i < 8; ++i) acc[i] = 0.f;
    const float4* w4 = (const float4*)(W + j * 128);
#pragma unroll 4
    for (int k = 0; k < 32; ++k) {
        float4 w = w4[k];
#pragma unroll
        for (int i = 0; i < 8; ++i) {
            float4 xv = ((const float4*)(xs + i * 128))[k];
            acc[i] += w.x * xv.x + w.y * xv.y + w.z * xv.z + w.w * xv.w;
        }
    }
    float bb = b[j];
#pragma unroll
    for (int i = 0; i < 8; ++i) x[(n0 + i) * 128 + j] = acc[i] + bb;
}

// build per-slot incident edge lists: one block per target slot scans all edges (int4 loads)
__global__ __launch_bounds__(256) void k_prep(const int* __restrict__ ei,
                                              const int* __restrict__ tp,
                                              int* __restrict__ cnt,
                                              int2* __restrict__ lst) {
    __shared__ int lc;
    const int slot = blockIdx.x;
    const int u = tp[slot];
    if (threadIdx.x == 0) lc = 0;
    __syncthreads();
    const int4* src4 = (const int4*)ei;
    const int4* dst4 = (const int4*)(ei + N_EDGES);
    for (int e4 = threadIdx.x; e4 < N_EDGES / 4; e4 += 256) {
        int4 s = src4[e4];
        int4 d = dst4[e4];
        int ss[4] = {s.x, s.y, s.z, s.w};
        int dd[4] = {d.x, d.y, d.z, d.w};
#pragma unroll
        for (int t = 0; t < 4; ++t) {
            if (ss[t] == u || dd[t] == u) {
                int nbr = (ss[t] == u) ? dd[t] : ss[t];
                int pos = atomicAdd(&lc, 1);
                if (pos < CAP) lst[slot * CAP + pos] = make_int2(e4 * 4 + t, nbr);
            }
        }
    }
    __syncthreads();
    if (threadIdx.x == 0) cnt[slot] = lc;
}

// per-slot: tf_u = ftb + ftW @ x[u];  q = bq + Wq @ tf_u
__global__ __launch_bounds__(128) void k_q(const float* __restrict__ x,
                                           const int* __restrict__ tp,
                                           const float* __restrict__ ftW,
                                           const float* __restrict__ ftb,
                                           const float* __restrict__ Wq,
                                           const float* __restrict__ bq,
                                           float* __restrict__ tfu_g,
                                           float* __restrict__ q_g,
                                           int relu_x) {
    __shared__ __align__(16) float xu[128], tf[128];
    const int slot = blockIdx.x;
    const int u = tp[slot];
    const int j = threadIdx.x;
    float v = x[u * 128 + j];
    xu[j] = relu_x ? fmaxf(v, 0.f) : v;
    __syncthreads();
    tf[j] = ftb[j] + dot128(ftW + j * 128, xu);
    __syncthreads();
    tfu_g[slot * 128 + j] = tf[j];
    q_g[slot * 128 + j] = bq[j] + dot128(Wq + j * 128, tf);
}

// per (slot, edge-entry): z = tf[nbr] + tfeat_e; k,v; per-head score
__global__ __launch_bounds__(128) void k_edge(
    const float* __restrict__ x, const float* __restrict__ ts,
    const int* __restrict__ cnt, const int2* __restrict__ lst,
    const float* __restrict__ ftW, const float* __restrict__ ftb,
    const float* __restrict__ teW1, const float* __restrict__ teb1,
    const float* __restrict__ teW2, const float* __restrict__ teb2,
    const float* __restrict__ Wk, const float* __restrict__ bk,
    const float* __restrict__ Wv, const float* __restrict__ bv,
    const float* __restrict__ q_g,
    float* __restrict__ scores, float* __restrict__ vbuf, int relu_x) {
    const int slot = blockIdx.x;
    const int j = threadIdx.x;
    const int c = min(cnt[slot], CAP);
    if ((int)blockIdx.y >= c) return;
    __shared__ __align__(16) float xn[128], t1[128], z[128];
    const float scale = 0.17677669529663687f;  // 1/sqrt(32)
    const float qj = q_g[slot * 128 + j];
    for (int i = blockIdx.y; i < c; i += EDGE_SPLIT) {
        int2 en = lst[slot * CAP + i];
        const float tse = ts[en.x];
        float xv = x[en.y * 128 + j];
        xn[j] = relu_x ? fmaxf(xv, 0.f) : xv;
        t1[j] = fmaxf(tse * teW1[j] + teb1[j], 0.f);
        __syncthreads();
        z[j] = teb2[j] + dot128(teW2 + j * 128, t1) + ftb[j] +
               dot128(ftW + j * 128, xn);
        __syncthreads();
        float kk = bk[j] + dot128(Wk + j * 128, z);
        float vv = bv[j] + dot128(Wv + j * 128, z);
        float prod = qj * kk;
        // reduce over the 32 lanes of each head (heads = 32 consecutive threads)
        prod += __shfl_xor(prod, 1);
        prod += __shfl_xor(prod, 2);
        prod += __shfl_xor(prod, 4);
        prod += __shfl_xor(prod, 8);
        prod += __shfl_xor(prod, 16);
        if ((j & 31) == 0) scores[(slot * CAP + i) * 4 + (j >> 5)] = prod * scale;
        vbuf[(slot * CAP + i) * 128 + j] = vv;
        __syncthreads();  // protect xn/t1 rewrite next iter vs z-reads this iter
    }
}

// per-slot: softmax over scores, weighted v-sum, attn_out, op
__global__ __launch_bounds__(128) void k_reduce(
    const int* __restrict__ cnt, const float* __restrict__ scores,
    const float* __restrict__ vbuf, const float* __restrict__ tfu_g,
    const float* __restrict__ aoW, const float* __restrict__ aob,
    const float* __restrict__ opW, const float* __restrict__ opb,
    float* __restrict__ agg) {
    __shared__ __align__(16) float outv[128], z[128];
    const int slot = blockIdx.x;
    const int j = threadIdx.x;
    const int h = j >> 5;
    const int c = min(cnt[slot], CAP);
    if (c > 0) {
        float m = -INFINITY;
        for (int i = 0; i < c; ++i)
            m = fmaxf(m, scores[(slot * CAP + i) * 4 + h]);
        float l = 0.f, o = 0.f;
        for (int i = 0; i < c; ++i) {
            float p = __expf(scores[(slot * CAP + i) * 4 + h] - m);
            l += p;
            o += p * vbuf[(slot * CAP + i) * 128 + j];
        }
        outv[j] = o / l;
    }
    __syncthreads();
    if (c > 0)
        z[j] = aob[j] + dot128(aoW + j * 128, outv);
    else
        z[j] = tfu_g[slot * 128 + j];
    __syncthreads();
    agg[slot * 128 + j] = opb[j] + dot128(opW + j * 128, z);
}

// scatter relu(agg) into x at target rows (duplicates write identical values)
__global__ void k_scatter(float* __restrict__ x, const float* __restrict__ agg,
                          const int* __restrict__ tp) {
    const int slot = blockIdx.x;
    const int j = threadIdx.x;
    const int u = tp[slot];
    x[u * 128 + j] = fmaxf(agg[slot * 128 + j], 0.f);
}

// emb only at target slots: emb = relu(relu(agg2) @ out1.T + b1) @ out2.T + b2
__global__ __launch_bounds__(128) void k_emb(const float* __restrict__ agg,
                                             const float* __restrict__ o1W,
                                             const float* __restrict__ o1b,
                                             const float* __restrict__ o2W,
                                             const float* __restrict__ o2b,
                                             float* __restrict__ emb) {
    __shared__ __align__(16) float xt[128], e1[128];
    const int slot = blockIdx.x;
    const int j = threadIdx.x;
    xt[j] = fmaxf(agg[slot * 128 + j], 0.f);
    __syncthreads();
    e1[j] = fmaxf(o1b[j] + dot128(o1W + j * 128, xt), 0.f);
    __syncthreads();
    if (j < 64) emb[slot * 64 + j] = o2b[j] + dot128(o2W + j * 128, e1);
}

__global__ __launch_bounds__(128) void k_pair(const float* __restrict__ emb,
                                              const float* __restrict__ l1W,
                                              const float* __restrict__ l1b,
                                              const float* __restrict__ l2W,
                                              const float* __restrict__ l2b,
                                              const float* __restrict__ l3W,
                                              const float* __restrict__ l3b,
                                              float* __restrict__ out) {
    __shared__ __align__(16) float pv[128], z1[128], z2s[64];
    const int p = blockIdx.x;
    const int j = threadIdx.x;
    pv[j] = (j < 64) ? emb[(2 * p) * 64 + j] : emb[(2 * p + 1) * 64 + (j - 64)];
    __syncthreads();
    z1[j] = fmaxf(l1b[j] + dot128(l1W + j * 128, pv), 0.f);
    __syncthreads();
    if (j < 64) z2s[j] = fmaxf(l2b[j] + dot128(l2W + j * 128, z1), 0.f);
    __syncthreads();
    if (j == 0) {
        float s = l3b[0];
#pragma unroll
        for (int k = 0; k < 64; ++k) s += l3W[k] * z2s[k];
        out[p] = 1.f / (1.f + __expf(-s));
    }
}

// ---------- launch ----------
extern "C" void kernel_launch(void* const* d_in, const int* in_sizes, int n_in,
                              void* d_out, int out_size, void* d_ws, size_t ws_size,
                              hipStream_t stream) {
    const float* nf  = (const float*)d_in[0];
    const int*   ei  = (const int*)d_in[1];
    const float* ts  = (const float*)d_in[2];
    const int*   tp  = (const int*)d_in[3];
    const float* inW = (const float*)d_in[4];
    const float* inb = (const float*)d_in[5];
    const float* teW1 = (const float*)d_in[6];
    const float* teb1 = (const float*)d_in[7];
    const float* teW2 = (const float*)d_in[8];
    const float* teb2 = (const float*)d_in[9];
    const float* aiW = (const float*)d_in[10];
    const float* aib = (const float*)d_in[11];
    const float* aoW = (const float*)d_in[12];
    const float* aob = (const float*)d_in[13];
    const float* ftW = (const float*)d_in[14];
    const float* ftb = (const float*)d_in[15];
    const float* opW = (const float*)d_in[16];
    const float* opb = (const float*)d_in[17];
    const float* o1W = (const float*)d_in[18];
    const float* o1b = (const float*)d_in[19];
    const float* o2W = (const float*)d_in[20];
    const float* o2b = (const float*)d_in[21];
    const float* l1W = (const float*)d_in[22];
    const float* l1b = (const float*)d_in[23];
    const float* l2W = (const float*)d_in[24];
    const float* l2b = (const float*)d_in[25];
    const float* l3W = (const float*)d_in[26];
    const float* l3b = (const float*)d_in[27];
    float* out = (float*)d_out;

    char* ws = (char*)d_ws;
    size_t off = 0;
    float* x    = (float*)(ws + off); off += (size_t)N_NODES * 128 * 4;      // 10.24 MB
    float* agg  = (float*)(ws + off); off += N_SLOTS * 128 * 4;
    float* emb  = (float*)(ws + off); off += N_SLOTS * 64 * 4;
    int*   cnt  = (int*)  (ws + off); off += N_SLOTS * 4;
    int2*  lst  = (int2*) (ws + off); off += (size_t)N_SLOTS * CAP * 8;
    float* tfu  = (float*)(ws + off); off += N_SLOTS * 128 * 4;
    float* qb   = (float*)(ws + off); off += N_SLOTS * 128 * 4;
    float* scb  = (float*)(ws + off); off += (size_t)N_SLOTS * CAP * 4 * 4;
    float* vbuf = (float*)(ws + off); off += (size_t)N_SLOTS * CAP * 128 * 4; // 8.4 MB

    k_in_proj<<<N_NODES / 8, 128, 0, stream>>>(nf, inW, inb, x);
    k_prep<<<N_SLOTS, 256, 0, stream>>>(ei, tp, cnt, lst);

    for (int l = 0; l < 2; ++l) {
        const float* Wq = aiW + l * 49152;
        const float* Wk = Wq + 128 * 128;
        const float* Wv = Wk + 128 * 128;
        const float* bq = aib + l * 384;
        const float* bk = bq + 128;
        const float* bv = bk + 128;
        const int relu_x = (l == 1);
        k_q<<<N_SLOTS, 128, 0, stream>>>(x, tp, ftW + l * 16384, ftb + l * 128,
                                         Wq, bq, tfu, qb, relu_x);
        k_edge<<<dim3(N_SLOTS, EDGE_SPLIT), 128, 0, stream>>>(
            x, ts, cnt, lst, ftW + l * 16384, ftb + l * 128,
            teW1 + l * 128, teb1 + l * 128, teW2 + l * 16384, teb2 + l * 128,
            Wk, bk, Wv, bv, qb, scb, vbuf, relu_x);
        k_reduce<<<N_SLOTS, 128, 0, stream>>>(cnt, scb, vbuf, tfu,
                                              aoW + l * 16384, aob + l * 128,
                                              opW + l * 16384, opb + l * 128, agg);
        if (l == 0) k_scatter<<<N_SLOTS, 128, 0, stream>>>(x, agg, tp);
    }
    k_emb<<<N_SLOTS, 128, 0, stream>>>(agg, o1W, o1b, o2W, o2b, emb);
    k_pair<<<N_PAIRS, 128, 0, stream>>>(emb, l1W, l1b, l2W, l2b, l3W, l3b, out);
}

// Round 3
// 370.380 us; speedup vs baseline: 1.2228x; 1.2025x over previous
//
#include <hip/hip_runtime.h>
#include <math.h>

#define N_NODES 20000
#define N_EDGES 50000
#define HID 128
#define OUT_DIM 64
#define N_SLOTS 256   // N_PAIRS * 2 flattened targets
#define N_PAIRS 128
#define CAP 64        // max incident edges stored per target slot (deg ~ Poisson(5))
#define EDGE_SPLIT 16 // gridDim.y of k_edge

// ---------- helpers ----------
// Bounded unroll: full unroll of 32 float4 iters made the compiler hoist ~128
// VGPRs of loads per dot -> >256 VGPR -> scratch spill -> 145 MB/launch traffic
// (R2 k_edge: VGPR=256, WRITE 98 MB). unroll 4 keeps the live set ~32 regs.
__device__ __forceinline__ float dot128(const float* __restrict__ w,
                                        const float* __restrict__ xs) {
    const float4* w4 = (const float4*)w;
    const float4* x4 = (const float4*)xs;
    float acc = 0.f;
#pragma unroll 4
    for (int k = 0; k < 32; ++k) {
        float4 a = w4[k];
        float4 b = x4[k];
        acc = fmaf(a.x, b.x, fmaf(a.y, b.y, fmaf(a.z, b.z, fmaf(a.w, b.w, acc))));
    }
    return acc;
}

// two dots sharing the x-vector loads (Wk/Wv rows vs same z)
__device__ __forceinline__ void dot128x2(const float* __restrict__ wa,
                                         const float* __restrict__ wb,
                                         const float* __restrict__ xs,
                                         float& ra, float& rb) {
    const float4* a4 = (const float4*)wa;
    const float4* b4 = (const float4*)wb;
    const float4* x4 = (const float4*)xs;
    float accA = 0.f, accB = 0.f;
#pragma unroll 2
    for (int k = 0; k < 32; ++k) {
        float4 xv = x4[k];
        float4 a = a4[k];
        float4 b = b4[k];
        accA = fmaf(a.x, xv.x, fmaf(a.y, xv.y, fmaf(a.z, xv.z, fmaf(a.w, xv.w, accA))));
        accB = fmaf(b.x, xv.x, fmaf(b.y, xv.y, fmaf(b.z, xv.z, fmaf(b.w, xv.w, accB))));
    }
    ra += accA;
    rb += accB;
}

// ---------- kernels ----------

// x0[n][j] = in_b[j] + sum_k in_W[j][k] * nf[n][k]   (8 nodes per block, 128 threads)
__global__ __launch_bounds__(128) void k_in_proj(const float* __restrict__ nf,
                                                 const float* __restrict__ W,
                                                 const float* __restrict__ b,
                                                 float* __restrict__ x) {
    __shared__ __align__(16) float xs[8 * 128];
    const int n0 = blockIdx.x * 8;
    const int j = threadIdx.x;
    for (int idx = j; idx < 8 * 128; idx += 128) xs[idx] = nf[n0 * 128 + idx];
    __syncthreads();
    float acc[8];
#pragma unroll
    for (int i = 0; i < 8; ++i) acc[i] = 0.f;
    const float4* w4 = (const float4*)(W + j * 128);
#pragma unroll 2
    for (int k = 0; k < 32; ++k) {
        float4 w = w4[k];
#pragma unroll
        for (int i = 0; i < 8; ++i) {
            float4 xv = ((const float4*)(xs + i * 128))[k];
            acc[i] = fmaf(w.x, xv.x, fmaf(w.y, xv.y, fmaf(w.z, xv.z, fmaf(w.w, xv.w, acc[i]))));
        }
    }
    float bb = b[j];
#pragma unroll
    for (int i = 0; i < 8; ++i) x[(n0 + i) * 128 + j] = acc[i] + bb;
}

// build per-slot incident edge lists: one block per target slot scans all edges (int4 loads)
__global__ __launch_bounds__(256) void k_prep(const int* __restrict__ ei,
                                              const int* __restrict__ tp,
                                              int* __restrict__ cnt,
                                              int2* __restrict__ lst) {
    __shared__ int lc;
    const int slot = blockIdx.x;
    const int u = tp[slot];
    if (threadIdx.x == 0) lc = 0;
    __syncthreads();
    const int4* src4 = (const int4*)ei;
    const int4* dst4 = (const int4*)(ei + N_EDGES);
    for (int e4 = threadIdx.x; e4 < N_EDGES / 4; e4 += 256) {
        int4 s = src4[e4];
        int4 d = dst4[e4];
        int ss[4] = {s.x, s.y, s.z, s.w};
        int dd[4] = {d.x, d.y, d.z, d.w};
#pragma unroll
        for (int t = 0; t < 4; ++t) {
            if (ss[t] == u || dd[t] == u) {
                int nbr = (ss[t] == u) ? dd[t] : ss[t];
                int pos = atomicAdd(&lc, 1);
                if (pos < CAP) lst[slot * CAP + pos] = make_int2(e4 * 4 + t, nbr);
            }
        }
    }
    __syncthreads();
    if (threadIdx.x == 0) cnt[slot] = lc;
}

// per-slot: tf_u = ftb + ftW @ x[u];  q = bq + Wq @ tf_u
__global__ __launch_bounds__(128) void k_q(const float* __restrict__ x,
                                           const int* __restrict__ tp,
                                           const float* __restrict__ ftW,
                                           const float* __restrict__ ftb,
                                           const float* __restrict__ Wq,
                                           const float* __restrict__ bq,
                                           float* __restrict__ tfu_g,
                                           float* __restrict__ q_g,
                                           int relu_x) {
    __shared__ __align__(16) float xu[128], tf[128];
    const int slot = blockIdx.x;
    const int u = tp[slot];
    const int j = threadIdx.x;
    float v = x[u * 128 + j];
    xu[j] = relu_x ? fmaxf(v, 0.f) : v;
    __syncthreads();
    tf[j] = ftb[j] + dot128(ftW + j * 128, xu);
    __syncthreads();
    tfu_g[slot * 128 + j] = tf[j];
    q_g[slot * 128 + j] = bq[j] + dot128(Wq + j * 128, tf);
}

// per (slot, edge-entry): z = tf[nbr] + tfeat_e; k,v; per-head score
__global__ __launch_bounds__(128) void k_edge(
    const float* __restrict__ x, const float* __restrict__ ts,
    const int* __restrict__ cnt, const int2* __restrict__ lst,
    const float* __restrict__ ftW, const float* __restrict__ ftb,
    const float* __restrict__ teW1, const float* __restrict__ teb1,
    const float* __restrict__ teW2, const float* __restrict__ teb2,
    const float* __restrict__ Wk, const float* __restrict__ bk,
    const float* __restrict__ Wv, const float* __restrict__ bv,
    const float* __restrict__ q_g,
    float* __restrict__ scores, float* __restrict__ vbuf, int relu_x) {
    const int slot = blockIdx.x;
    const int j = threadIdx.x;
    const int c = min(cnt[slot], CAP);
    if ((int)blockIdx.y >= c) return;
    __shared__ __align__(16) float xn[128], t1[128], z[128];
    const float scale = 0.17677669529663687f;  // 1/sqrt(32)
    const float qj = q_g[slot * 128 + j];
    for (int i = blockIdx.y; i < c; i += EDGE_SPLIT) {
        int2 en = lst[slot * CAP + i];
        const float tse = ts[en.x];
        float xv = x[en.y * 128 + j];
        xn[j] = relu_x ? fmaxf(xv, 0.f) : xv;
        t1[j] = fmaxf(tse * teW1[j] + teb1[j], 0.f);
        __syncthreads();
        float zj = teb2[j] + ftb[j];
        dot128x2(teW2 + j * 128, ftW + j * 128, t1, zj, zj);  // careful: needs distinct x
        // NOTE: teW2 acts on t1, ftW acts on xn -> cannot share x loads; do separately:
        z[j] = zj;  // placeholder overwritten below
        z[j] = teb2[j] + dot128(teW2 + j * 128, t1) + ftb[j] +
               dot128(ftW + j * 128, xn);
        __syncthreads();
        float kk = bk[j], vv = bv[j];
        dot128x2(Wk + j * 128, Wv + j * 128, z, kk, vv);
        float prod = qj * kk;
        // reduce over the 32 lanes of each head (heads = 32 consecutive threads)
        prod += __shfl_xor(prod, 1);
        prod += __shfl_xor(prod, 2);
        prod += __shfl_xor(prod, 4);
        prod += __shfl_xor(prod, 8);
        prod += __shfl_xor(prod, 16);
        if ((j & 31) == 0) scores[(slot * CAP + i) * 4 + (j >> 5)] = prod * scale;
        vbuf[(slot * CAP + i) * 128 + j] = vv;
        __syncthreads();  // protect xn/t1 rewrite next iter vs z-reads this iter
    }
}

// per-slot: softmax over scores, weighted v-sum, attn_out, op.
// mode 0: scatter relu(agg) into x at target row.
// mode 1: run the emb head (relu -> out1 -> relu -> out2) and write emb.
__global__ __launch_bounds__(128) void k_reduce(
    const int* __restrict__ cnt, const float* __restrict__ scores,
    const float* __restrict__ vbuf, const float* __restrict__ tfu_g,
    const float* __restrict__ aoW, const float* __restrict__ aob,
    const float* __restrict__ opW, const float* __restrict__ opb,
    const int* __restrict__ tp, float* __restrict__ x_out,
    const float* __restrict__ o1W, const float* __restrict__ o1b,
    const float* __restrict__ o2W, const float* __restrict__ o2b,
    float* __restrict__ emb, int mode) {
    __shared__ __align__(16) float outv[128], z[128], xt[128], e1[128];
    const int slot = blockIdx.x;
    const int j = threadIdx.x;
    const int h = j >> 5;
    const int c = min(cnt[slot], CAP);
    if (c > 0) {
        float m = -INFINITY;
        for (int i = 0; i < c; ++i)
            m = fmaxf(m, scores[(slot * CAP + i) * 4 + h]);
        float l = 0.f, o = 0.f;
        for (int i = 0; i < c; ++i) {
            float p = __expf(scores[(slot * CAP + i) * 4 + h] - m);
            l += p;
            o = fmaf(p, vbuf[(slot * CAP + i) * 128 + j], o);
        }
        outv[j] = o / l;
    }
    __syncthreads();
    if (c > 0)
        z[j] = aob[j] + dot128(aoW + j * 128, outv);
    else
        z[j] = tfu_g[slot * 128 + j];
    __syncthreads();
    float aggj = opb[j] + dot128(opW + j * 128, z);
    if (mode == 0) {
        const int u = tp[slot];
        x_out[u * 128 + j] = fmaxf(aggj, 0.f);  // duplicates write identical values
    } else {
        xt[j] = fmaxf(aggj, 0.f);
        __syncthreads();
        e1[j] = fmaxf(o1b[j] + dot128(o1W + j * 128, xt), 0.f);
        __syncthreads();
        if (j < 64) emb[slot * 64 + j] = o2b[j] + dot128(o2W + j * 128, e1);
    }
}

__global__ __launch_bounds__(128) void k_pair(const float* __restrict__ emb,
                                              const float* __restrict__ l1W,
                                              const float* __restrict__ l1b,
                                              const float* __restrict__ l2W,
                                              const float* __restrict__ l2b,
                                              const float* __restrict__ l3W,
                                              const float* __restrict__ l3b,
                                              float* __restrict__ out) {
    __shared__ __align__(16) float pv[128], z1[128], z2s[64];
    const int p = blockIdx.x;
    const int j = threadIdx.x;
    pv[j] = (j < 64) ? emb[(2 * p) * 64 + j] : emb[(2 * p + 1) * 64 + (j - 64)];
    __syncthreads();
    z1[j] = fmaxf(l1b[j] + dot128(l1W + j * 128, pv), 0.f);
    __syncthreads();
    if (j < 64) z2s[j] = fmaxf(l2b[j] + dot128(l2W + j * 128, z1), 0.f);
    __syncthreads();
    if (j == 0) {
        float s = l3b[0];
#pragma unroll 8
        for (int k = 0; k < 64; ++k) s = fmaf(l3W[k], z2s[k], s);
        out[p] = 1.f / (1.f + __expf(-s));
    }
}

// ---------- launch ----------
extern "C" void kernel_launch(void* const* d_in, const int* in_sizes, int n_in,
                              void* d_out, int out_size, void* d_ws, size_t ws_size,
                              hipStream_t stream) {
    const float* nf  = (const float*)d_in[0];
    const int*   ei  = (const int*)d_in[1];
    const float* ts  = (const float*)d_in[2];
    const int*   tp  = (const int*)d_in[3];
    const float* inW = (const float*)d_in[4];
    const float* inb = (const float*)d_in[5];
    const float* teW1 = (const float*)d_in[6];
    const float* teb1 = (const float*)d_in[7];
    const float* teW2 = (const float*)d_in[8];
    const float* teb2 = (const float*)d_in[9];
    const float* aiW = (const float*)d_in[10];
    const float* aib = (const float*)d_in[11];
    const float* aoW = (const float*)d_in[12];
    const float* aob = (const float*)d_in[13];
    const float* ftW = (const float*)d_in[14];
    const float* ftb = (const float*)d_in[15];
    const float* opW = (const float*)d_in[16];
    const float* opb = (const float*)d_in[17];
    const float* o1W = (const float*)d_in[18];
    const float* o1b = (const float*)d_in[19];
    const float* o2W = (const float*)d_in[20];
    const float* o2b = (const float*)d_in[21];
    const float* l1W = (const float*)d_in[22];
    const float* l1b = (const float*)d_in[23];
    const float* l2W = (const float*)d_in[24];
    const float* l2b = (const float*)d_in[25];
    const float* l3W = (const float*)d_in[26];
    const float* l3b = (const float*)d_in[27];
    float* out = (float*)d_out;

    char* ws = (char*)d_ws;
    size_t off = 0;
    float* x    = (float*)(ws + off); off += (size_t)N_NODES * 128 * 4;      // 10.24 MB
    float* emb  = (float*)(ws + off); off += N_SLOTS * 64 * 4;
    int*   cnt  = (int*)  (ws + off); off += N_SLOTS * 4;
    int2*  lst  = (int2*) (ws + off); off += (size_t)N_SLOTS * CAP * 8;
    float* tfu  = (float*)(ws + off); off += N_SLOTS * 128 * 4;
    float* qb   = (float*)(ws + off); off += N_SLOTS * 128 * 4;
    float* scb  = (float*)(ws + off); off += (size_t)N_SLOTS * CAP * 4 * 4;
    float* vbuf = (float*)(ws + off); off += (size_t)N_SLOTS * CAP * 128 * 4; // 8.4 MB

    k_in_proj<<<N_NODES / 8, 128, 0, stream>>>(nf, inW, inb, x);
    k_prep<<<N_SLOTS, 256, 0, stream>>>(ei, tp, cnt, lst);

    for (int l = 0; l < 2; ++l) {
        const float* Wq = aiW + l * 49152;
        const float* Wk = Wq + 128 * 128;
        const float* Wv = Wk + 128 * 128;
        const float* bq = aib + l * 384;
        const float* bk = bq + 128;
        const float* bv = bk + 128;
        const int relu_x = (l == 1);
        k_q<<<N_SLOTS, 128, 0, stream>>>(x, tp, ftW + l * 16384, ftb + l * 128,
                                         Wq, bq, tfu, qb, relu_x);
        k_edge<<<dim3(N_SLOTS, EDGE_SPLIT), 128, 0, stream>>>(
            x, ts, cnt, lst, ftW + l * 16384, ftb + l * 128,
            teW1 + l * 128, teb1 + l * 128, teW2 + l * 16384, teb2 + l * 128,
            Wk, bk, Wv, bv, qb, scb, vbuf, relu_x);
        k_reduce<<<N_SLOTS, 128, 0, stream>>>(
            cnt, scb, vbuf, tfu, aoW + l * 16384, aob + l * 128,
            opW + l * 16384, opb + l * 128, tp, x,
            o1W, o1b, o2W, o2b, emb, l);
    }
    k_pair<<<N_PAIRS, 128, 0, stream>>>(emb, l1W, l1b, l2W, l2b, l3W, l3b, out);
}

// Round 4
// 324.132 us; speedup vs baseline: 1.3972x; 1.1427x over previous
//
#include <hip/hip_runtime.h>
#include <math.h>

#define N_NODES 20000
#define N_EDGES 50000
#define HID 128
#define OUT_DIM 64
#define N_SLOTS 256   // N_PAIRS * 2 flattened targets
#define N_PAIRS 128
#define CAP 64        // max incident edges per slot (deg ~ Poisson(5); P(>64) ~ 0)
#define MSTRIDE 16384 // floats per transposed-matrix slot in ws
#define NMAT 19

// ---------- helpers ----------
__device__ __forceinline__ float4 relu4(float4 v) {
    return make_float4(fmaxf(v.x, 0.f), fmaxf(v.y, 0.f), fmaxf(v.z, 0.f), fmaxf(v.w, 0.f));
}
__device__ __forceinline__ float4 add4(float4 a, float4 b) {
    return make_float4(a.x + b.x, a.y + b.y, a.z + b.z, a.w + b.w);
}
__device__ __forceinline__ void fma4(float4& acc, const float4 w, const float s) {
    acc.x = fmaf(w.x, s, acc.x); acc.y = fmaf(w.y, s, acc.y);
    acc.z = fmaf(w.z, s, acc.z); acc.w = fmaf(w.w, s, acc.w);
}
#define F4Z make_float4(0.f, 0.f, 0.f, 0.f)

// y_e[j4] += sum_k WT[k][j4] * x_e[k]; thread (g=tid>>5, jj=tid&31) handles
// outputs j = 4*jj..4*jj+3 for items e in {g*EPG..g*EPG+EPG-1}. WT coalesced.
template<int EPG>
__device__ __forceinline__ void mvT1(const float* __restrict__ WT,
                                     const float* __restrict__ xs,
                                     int g, int jj, float4* acc) {
    const float4* W4 = (const float4*)WT;
    const float4* x4 = (const float4*)xs;
#pragma unroll 2
    for (int k4 = 0; k4 < 32; ++k4) {
        float4 w0 = W4[(k4 * 4 + 0) * 32 + jj];
        float4 w1 = W4[(k4 * 4 + 1) * 32 + jj];
        float4 w2 = W4[(k4 * 4 + 2) * 32 + jj];
        float4 w3 = W4[(k4 * 4 + 3) * 32 + jj];
#pragma unroll
        for (int e = 0; e < EPG; ++e) {
            float4 xv = x4[(g * EPG + e) * 32 + k4];
            fma4(acc[e], w0, xv.x); fma4(acc[e], w1, xv.y);
            fma4(acc[e], w2, xv.z); fma4(acc[e], w3, xv.w);
        }
    }
}

// two matrices (possibly two different LDS inputs) sharing the loop
template<int EPG>
__device__ __forceinline__ void mvT2(const float* __restrict__ WTa,
                                     const float* __restrict__ WTb,
                                     const float* __restrict__ xa,
                                     const float* __restrict__ xb,
                                     int g, int jj, float4* acca, float4* accb) {
    const float4* A4 = (const float4*)WTa;
    const float4* B4 = (const float4*)WTb;
    const float4* xa4 = (const float4*)xa;
    const float4* xb4 = (const float4*)xb;
#pragma unroll 2
    for (int k4 = 0; k4 < 32; ++k4) {
        float4 a0 = A4[(k4 * 4 + 0) * 32 + jj], a1 = A4[(k4 * 4 + 1) * 32 + jj],
               a2 = A4[(k4 * 4 + 2) * 32 + jj], a3 = A4[(k4 * 4 + 3) * 32 + jj];
        float4 b0 = B4[(k4 * 4 + 0) * 32 + jj], b1 = B4[(k4 * 4 + 1) * 32 + jj],
               b2 = B4[(k4 * 4 + 2) * 32 + jj], b3 = B4[(k4 * 4 + 3) * 32 + jj];
#pragma unroll
        for (int e = 0; e < EPG; ++e) {
            float4 xv = xa4[(g * EPG + e) * 32 + k4];
            float4 yv = xb4[(g * EPG + e) * 32 + k4];
            fma4(acca[e], a0, xv.x); fma4(acca[e], a1, xv.y);
            fma4(acca[e], a2, xv.z); fma4(acca[e], a3, xv.w);
            fma4(accb[e], b0, yv.x); fma4(accb[e], b1, yv.y);
            fma4(accb[e], b2, yv.z); fma4(accb[e], b3, yv.w);
        }
    }
}

// 64-output variant: only jj<16 lanes carry real outputs (others compute dup)
template<int EPG>
__device__ __forceinline__ void mvT1_64(const float* __restrict__ WT,
                                        const float* __restrict__ xs,
                                        int g, int jj, float4* acc) {
    const float4* W4 = (const float4*)WT;
    const float4* x4 = (const float4*)xs;
    int j16 = jj & 15;
#pragma unroll 2
    for (int k4 = 0; k4 < 32; ++k4) {
        float4 w0 = W4[(k4 * 4 + 0) * 16 + j16];
        float4 w1 = W4[(k4 * 4 + 1) * 16 + j16];
        float4 w2 = W4[(k4 * 4 + 2) * 16 + j16];
        float4 w3 = W4[(k4 * 4 + 3) * 16 + j16];
#pragma unroll
        for (int e = 0; e < EPG; ++e) {
            float4 xv = x4[(g * EPG + e) * 32 + k4];
            fma4(acc[e], w0, xv.x); fma4(acc[e], w1, xv.y);
            fma4(acc[e], w2, xv.z); fma4(acc[e], w3, xv.w);
        }
    }
}

// ---------- kernels ----------

// transpose the 19 weight matrices W[rows][128] -> WT[128][rows]; zero gcnt
__global__ __launch_bounds__(256) void k_tr(
    const float* __restrict__ inW, const float* __restrict__ ftW,
    const float* __restrict__ teW2, const float* __restrict__ aiW,
    const float* __restrict__ aoW, const float* __restrict__ opW,
    const float* __restrict__ o1W, const float* __restrict__ o2W,
    const float* __restrict__ l1W, const float* __restrict__ l2W,
    float* __restrict__ WT, int* __restrict__ gcnt) {
    __shared__ float tile[32][129];
    const int m = blockIdx.x;
    if (m == 0 && threadIdx.x == 0) gcnt[0] = 0;
    const float* src;
    int rows = 128;
    if (m == 0) src = inW;
    else if (m <= 2) src = ftW + (m - 1) * MSTRIDE;
    else if (m <= 4) src = teW2 + (m - 3) * MSTRIDE;
    else if (m <= 10) src = aiW + (m - 5) * MSTRIDE;   // q,k,v L0 then q,k,v L1
    else if (m <= 12) src = aoW + (m - 11) * MSTRIDE;
    else if (m <= 14) src = opW + (m - 13) * MSTRIDE;
    else if (m == 15) src = o1W;
    else if (m == 16) src = l1W;
    else if (m == 17) { src = o2W; rows = 64; }
    else { src = l2W; rows = 64; }
    float* dst = WT + m * MSTRIDE;
    for (int r0 = 0; r0 < rows; r0 += 32) {
        __syncthreads();
        for (int idx = threadIdx.x; idx < 32 * 128; idx += 256) {
            int r = idx >> 7, c = idx & 127;
            tile[r][c] = src[(r0 + r) * 128 + c];
        }
        __syncthreads();
        for (int idx = threadIdx.x; idx < 128 * 32; idx += 256) {
            int k = idx >> 5, jr = idx & 31;
            dst[k * rows + r0 + jr] = tile[jr][k];
        }
    }
}

// x0 = nf @ inW.T + inb, 8 nodes per block, coalesced transposed weights
__global__ __launch_bounds__(128) void k_in_proj2(const float* __restrict__ nf,
                                                  const float* __restrict__ WT_in,
                                                  const float* __restrict__ inb,
                                                  float* __restrict__ x) {
    __shared__ __align__(16) float xs[8 * 128];
    const int tid = threadIdx.x, g = tid >> 5, jj = tid & 31;
    const int n0 = blockIdx.x * 8;
    const float4* src = (const float4*)(nf + (size_t)n0 * 128);
    float4* dl = (float4*)xs;
    dl[tid] = src[tid];
    dl[tid + 128] = src[tid + 128];
    __syncthreads();
    float4 acc[2] = {F4Z, F4Z};
    mvT1<2>(WT_in, xs, g, jj, acc);
    float4 b4 = *(const float4*)(inb + jj * 4);
#pragma unroll
    for (int e = 0; e < 2; ++e) {
        int eg = g * 2 + e;
        *(float4*)(x + (size_t)(n0 + eg) * 128 + jj * 4) = add4(acc[e], b4);
    }
}

// incident edge lists per slot + compact global (slot,i) entry list
__global__ __launch_bounds__(256) void k_prep(const int* __restrict__ ei,
                                              const int* __restrict__ tp,
                                              int* __restrict__ cnt,
                                              int2* __restrict__ lst,
                                              int* __restrict__ gl,
                                              int* __restrict__ gcnt) {
    __shared__ int lc;
    const int slot = blockIdx.x;
    const int u = tp[slot];
    if (threadIdx.x == 0) lc = 0;
    __syncthreads();
    const int4* src4 = (const int4*)ei;
    const int4* dst4 = (const int4*)(ei + N_EDGES);
    for (int e4 = threadIdx.x; e4 < N_EDGES / 4; e4 += 256) {
        int4 s = src4[e4];
        int4 d = dst4[e4];
        int ss[4] = {s.x, s.y, s.z, s.w};
        int dd[4] = {d.x, d.y, d.z, d.w};
#pragma unroll
        for (int t = 0; t < 4; ++t) {
            if (ss[t] == u || dd[t] == u) {
                int nbr = (ss[t] == u) ? dd[t] : ss[t];
                int pos = atomicAdd(&lc, 1);
                if (pos < CAP) {
                    lst[slot * CAP + pos] = make_int2(e4 * 4 + t, nbr);
                    int gp = atomicAdd(gcnt, 1);
                    gl[gp] = (slot << 6) | pos;
                }
            }
        }
    }
    __syncthreads();
    if (threadIdx.x == 0) cnt[slot] = lc;
}

// per-slot tf_u and q, 8 slots per block
__global__ __launch_bounds__(128) void k_q2(
    const float* __restrict__ x, const int* __restrict__ tp,
    const float* __restrict__ WT_ft, const float* __restrict__ ftb,
    const float* __restrict__ WT_q, const float* __restrict__ bq,
    float* __restrict__ tfu_g, float* __restrict__ q_g, int relu_x) {
    __shared__ __align__(16) float xu[8 * 128], tfs[8 * 128];
    __shared__ int u_s[8];
    const int tid = threadIdx.x, g = tid >> 5, jj = tid & 31;
    const int base = blockIdx.x * 8;
    if (tid < 8) u_s[tid] = tp[base + tid];
    __syncthreads();
    {
        int e = tid >> 4, c0 = (tid & 15) * 8;
        const float4* xr = (const float4*)(x + (size_t)u_s[e] * 128 + c0);
        float4 v0 = xr[0], v1 = xr[1];
        if (relu_x) { v0 = relu4(v0); v1 = relu4(v1); }
        *(float4*)(xu + e * 128 + c0) = v0;
        *(float4*)(xu + e * 128 + c0 + 4) = v1;
    }
    __syncthreads();
    float4 acc[2] = {F4Z, F4Z};
    mvT1<2>(WT_ft, xu, g, jj, acc);
    float4 fb = *(const float4*)(ftb + jj * 4);
#pragma unroll
    for (int e = 0; e < 2; ++e) {
        int eg = g * 2 + e;
        float4 t = add4(acc[e], fb);
        *(float4*)(tfs + eg * 128 + jj * 4) = t;
        *(float4*)(tfu_g + (size_t)(base + eg) * 128 + jj * 4) = t;
    }
    __syncthreads();
    float4 acc2[2] = {F4Z, F4Z};
    mvT1<2>(WT_q, tfs, g, jj, acc2);
    float4 qb4 = *(const float4*)(bq + jj * 4);
#pragma unroll
    for (int e = 0; e < 2; ++e) {
        int eg = g * 2 + e;
        *(float4*)(q_g + (size_t)(base + eg) * 128 + jj * 4) = add4(acc2[e], qb4);
    }
}

// batched per-entry edge work: z, k, v, per-head score; 8 entries per block
__global__ __launch_bounds__(128) void k_edge2(
    const float* __restrict__ x, const float* __restrict__ ts,
    const int2* __restrict__ lst, const int* __restrict__ gl,
    const int* __restrict__ gcnt,
    const float* __restrict__ teW1, const float* __restrict__ teb1,
    const float* __restrict__ WT_ft, const float* __restrict__ ftb,
    const float* __restrict__ WT_te2, const float* __restrict__ teb2,
    const float* __restrict__ WT_k, const float* __restrict__ bk,
    const float* __restrict__ WT_v, const float* __restrict__ bv,
    const float* __restrict__ q_g,
    float* __restrict__ scores, float* __restrict__ vbuf, int relu_x) {
    __shared__ __align__(16) float xs[8 * 128], t1s[8 * 128], zs[8 * 128];
    __shared__ int slot_s[8], pos_s[8], act_s[8], nbr_s[8];
    __shared__ float ts_s[8];
    const int tid = threadIdx.x, g = tid >> 5, jj = tid & 31;
    const float scale = 0.17677669529663687f;  // 1/sqrt(32)
    const int G = gcnt[0];
    for (int base = blockIdx.x * 8; base < G; base += 256 * 8) {
        if (tid < 8) {
            int ent = base + tid;
            int ok = (ent < G) ? 1 : 0;
            int pk = ok ? gl[ent] : 0;
            int slot = pk >> 6;
            slot_s[tid] = slot;
            pos_s[tid] = pk & 63;
            act_s[tid] = ok;
            int2 en = ok ? lst[slot * CAP + (pk & 63)] : make_int2(0, 0);
            nbr_s[tid] = en.y;
            ts_s[tid] = ok ? ts[en.x] : 0.f;
        }
        __syncthreads();
        {
            int e = tid >> 4, c0 = (tid & 15) * 8;
            const float4* xr = (const float4*)(x + (size_t)nbr_s[e] * 128 + c0);
            float4 v0 = xr[0], v1 = xr[1];
            if (relu_x) { v0 = relu4(v0); v1 = relu4(v1); }
            *(float4*)(xs + e * 128 + c0) = v0;
            *(float4*)(xs + e * 128 + c0 + 4) = v1;
            float tse = ts_s[e];
            float4 w0 = *(const float4*)(teW1 + c0);
            float4 w1 = *(const float4*)(teW1 + c0 + 4);
            float4 bb0 = *(const float4*)(teb1 + c0);
            float4 bb1 = *(const float4*)(teb1 + c0 + 4);
            float4 t0 = make_float4(fmaxf(fmaf(tse, w0.x, bb0.x), 0.f),
                                    fmaxf(fmaf(tse, w0.y, bb0.y), 0.f),
                                    fmaxf(fmaf(tse, w0.z, bb0.z), 0.f),
                                    fmaxf(fmaf(tse, w0.w, bb0.w), 0.f));
            float4 t1 = make_float4(fmaxf(fmaf(tse, w1.x, bb1.x), 0.f),
                                    fmaxf(fmaf(tse, w1.y, bb1.y), 0.f),
                                    fmaxf(fmaf(tse, w1.z, bb1.z), 0.f),
                                    fmaxf(fmaf(tse, w1.w, bb1.w), 0.f));
            *(float4*)(t1s + e * 128 + c0) = t0;
            *(float4*)(t1s + e * 128 + c0 + 4) = t1;
        }
        __syncthreads();
        float4 za[2] = {F4Z, F4Z}, zb[2] = {F4Z, F4Z};
        mvT2<2>(WT_ft, WT_te2, xs, t1s, g, jj, za, zb);
        float4 fb = *(const float4*)(ftb + jj * 4);
        float4 tb = *(const float4*)(teb2 + jj * 4);
#pragma unroll
        for (int e = 0; e < 2; ++e) {
            int eg = g * 2 + e;
            float4 z4 = add4(add4(za[e], zb[e]), add4(fb, tb));
            *(float4*)(zs + eg * 128 + jj * 4) = z4;
        }
        __syncthreads();
        float4 ka[2] = {F4Z, F4Z}, va[2] = {F4Z, F4Z};
        mvT2<2>(WT_k, WT_v, zs, zs, g, jj, ka, va);
        float4 kb4 = *(const float4*)(bk + jj * 4);
        float4 vb4 = *(const float4*)(bv + jj * 4);
#pragma unroll
        for (int e = 0; e < 2; ++e) {
            int eg = g * 2 + e;
            float4 kk = add4(ka[e], kb4);
            float4 vv = add4(va[e], vb4);
            float4 q4 = *(const float4*)(q_g + (size_t)slot_s[eg] * 128 + jj * 4);
            float pr = q4.x * kk.x + q4.y * kk.y + q4.z * kk.z + q4.w * kk.w;
            pr += __shfl_xor(pr, 1);
            pr += __shfl_xor(pr, 2);
            pr += __shfl_xor(pr, 4);   // sum over the 8 jj of head (jj>>3)
            if (act_s[eg]) {
                int pos = slot_s[eg] * CAP + pos_s[eg];
                if ((jj & 7) == 0) scores[pos * 4 + (jj >> 3)] = pr * scale;
                *(float4*)(vbuf + (size_t)pos * 128 + jj * 4) = vv;
            }
        }
        __syncthreads();
    }
}

// per-slot softmax + attn_out + op (+ scatter or emb head); 8 slots per block
__global__ __launch_bounds__(128) void k_reduce2(
    const int* __restrict__ cnt, const int* __restrict__ tp,
    const float* __restrict__ scores, const float* __restrict__ vbuf,
    const float* __restrict__ tfu_g,
    const float* __restrict__ WT_ao, const float* __restrict__ aob,
    const float* __restrict__ WT_op, const float* __restrict__ opb,
    float* __restrict__ x,
    const float* __restrict__ WT_o1, const float* __restrict__ o1b,
    const float* __restrict__ WT_o2, const float* __restrict__ o2b,
    float* __restrict__ emb, int mode) {
    __shared__ __align__(16) float outvs[8 * 128], zs[8 * 128];
    __shared__ int u_s[8], c_s[8];
    const int tid = threadIdx.x, g = tid >> 5, jj = tid & 31;
    const int base = blockIdx.x * 8;
    if (tid < 8) {
        u_s[tid] = tp[base + tid];
        c_s[tid] = min(cnt[base + tid], CAP);
    }
    __syncthreads();
    const int j = tid, h = j >> 5;
    for (int e = 0; e < 8; ++e) {
        int slot = base + e, c = c_s[e];
        if (c > 0) {
            float m = -INFINITY;
            for (int i = 0; i < c; ++i) m = fmaxf(m, scores[(slot * CAP + i) * 4 + h]);
            float l = 0.f, o = 0.f;
            for (int i = 0; i < c; ++i) {
                float p = __expf(scores[(slot * CAP + i) * 4 + h] - m);
                l += p;
                o = fmaf(p, vbuf[(size_t)(slot * CAP + i) * 128 + j], o);
            }
            outvs[e * 128 + j] = o / l;
        } else {
            outvs[e * 128 + j] = 0.f;  // keep LDS clean for the mvT below
        }
    }
    __syncthreads();
    float4 acc[2] = {F4Z, F4Z};
    mvT1<2>(WT_ao, outvs, g, jj, acc);
    float4 ab = *(const float4*)(aob + jj * 4);
#pragma unroll
    for (int e = 0; e < 2; ++e) {
        int eg = g * 2 + e;
        float4 z4;
        if (c_s[eg] > 0) z4 = add4(acc[e], ab);
        else z4 = *(const float4*)(tfu_g + (size_t)(base + eg) * 128 + jj * 4);
        *(float4*)(zs + eg * 128 + jj * 4) = z4;
    }
    __syncthreads();
    float4 acc2[2] = {F4Z, F4Z};
    mvT1<2>(WT_op, zs, g, jj, acc2);
    float4 ob = *(const float4*)(opb + jj * 4);
    if (mode == 0) {
#pragma unroll
        for (int e = 0; e < 2; ++e) {
            int eg = g * 2 + e;
            float4 a = relu4(add4(acc2[e], ob));  // relu folded into scatter
            *(float4*)(x + (size_t)u_s[eg] * 128 + jj * 4) = a;
        }
    } else {
        __syncthreads();  // outvs reuse below
#pragma unroll
        for (int e = 0; e < 2; ++e) {
            int eg = g * 2 + e;
            *(float4*)(outvs + eg * 128 + jj * 4) = relu4(add4(acc2[e], ob));
        }
        __syncthreads();
        float4 acc3[2] = {F4Z, F4Z};
        mvT1<2>(WT_o1, outvs, g, jj, acc3);
        float4 b1 = *(const float4*)(o1b + jj * 4);
#pragma unroll
        for (int e = 0; e < 2; ++e) {
            int eg = g * 2 + e;
            *(float4*)(zs + eg * 128 + jj * 4) = relu4(add4(acc3[e], b1));
        }
        __syncthreads();
        float4 acc4[2] = {F4Z, F4Z};
        mvT1_64<2>(WT_o2, zs, g, jj, acc4);
        if (jj < 16) {
            float4 b2 = *(const float4*)(o2b + jj * 4);
#pragma unroll
            for (int e = 0; e < 2; ++e) {
                int eg = g * 2 + e;
                *(float4*)(emb + (size_t)(base + eg) * 64 + jj * 4) = add4(acc4[e], b2);
            }
        }
    }
}

// pair head: 8 pairs per block
__global__ __launch_bounds__(128) void k_pair2(
    const float* __restrict__ emb,
    const float* __restrict__ WT_l1, const float* __restrict__ l1b,
    const float* __restrict__ WT_l2, const float* __restrict__ l2b,
    const float* __restrict__ l3W, const float* __restrict__ l3b,
    float* __restrict__ out) {
    __shared__ __align__(16) float pv[8 * 128], z1s[8 * 128], z2s[8 * 64];
    const int tid = threadIdx.x, g = tid >> 5, jj = tid & 31;
    const int base = blockIdx.x * 8;
    {
        int e = tid >> 4, c0 = (tid & 15) * 8;
        int p = base + e;
        const float* sp = (c0 < 64) ? (emb + (size_t)(2 * p) * 64 + c0)
                                    : (emb + (size_t)(2 * p + 1) * 64 + (c0 - 64));
        float4 v0 = *(const float4*)sp, v1 = *(const float4*)(sp + 4);
        *(float4*)(pv + e * 128 + c0) = v0;
        *(float4*)(pv + e * 128 + c0 + 4) = v1;
    }
    __syncthreads();
    float4 acc[2] = {F4Z, F4Z};
    mvT1<2>(WT_l1, pv, g, jj, acc);
    float4 b1 = *(const float4*)(l1b + jj * 4);
#pragma unroll
    for (int e = 0; e < 2; ++e) {
        int eg = g * 2 + e;
        *(float4*)(z1s + eg * 128 + jj * 4) = relu4(add4(acc[e], b1));
    }
    __syncthreads();
    float4 acc2[2] = {F4Z, F4Z};
    mvT1_64<2>(WT_l2, z1s, g, jj, acc2);
    if (jj < 16) {
        float4 b2 = *(const float4*)(l2b + jj * 4);
#pragma unroll
        for (int e = 0; e < 2; ++e) {
            int eg = g * 2 + e;
            *(float4*)(z2s + eg * 64 + jj * 4) = relu4(add4(acc2[e], b2));
        }
    }
    __syncthreads();
    if (tid < 8) {
        float s = l3b[0];
#pragma unroll 8
        for (int k = 0; k < 64; ++k) s = fmaf(l3W[k], z2s[tid * 64 + k], s);
        out[base + tid] = 1.f / (1.f + __expf(-s));
    }
}

// ---------- launch ----------
extern "C" void kernel_launch(void* const* d_in, const int* in_sizes, int n_in,
                              void* d_out, int out_size, void* d_ws, size_t ws_size,
                              hipStream_t stream) {
    const float* nf  = (const float*)d_in[0];
    const int*   ei  = (const int*)d_in[1];
    const float* ts  = (const float*)d_in[2];
    const int*   tp  = (const int*)d_in[3];
    const float* inW = (const float*)d_in[4];
    const float* inb = (const float*)d_in[5];
    const float* teW1 = (const float*)d_in[6];
    const float* teb1 = (const float*)d_in[7];
    const float* teW2 = (const float*)d_in[8];
    const float* teb2 = (const float*)d_in[9];
    const float* aiW = (const float*)d_in[10];
    const float* aib = (const float*)d_in[11];
    const float* aoW = (const float*)d_in[12];
    const float* aob = (const float*)d_in[13];
    const float* ftW = (const float*)d_in[14];
    const float* ftb = (const float*)d_in[15];
    const float* opW = (const float*)d_in[16];
    const float* opb = (const float*)d_in[17];
    const float* o1W = (const float*)d_in[18];
    const float* o1b = (const float*)d_in[19];
    const float* o2W = (const float*)d_in[20];
    const float* o2b = (const float*)d_in[21];
    const float* l1W = (const float*)d_in[22];
    const float* l1b = (const float*)d_in[23];
    const float* l2W = (const float*)d_in[24];
    const float* l2b = (const float*)d_in[25];
    const float* l3W = (const float*)d_in[26];
    const float* l3b = (const float*)d_in[27];
    float* out = (float*)d_out;

    char* ws = (char*)d_ws;
    size_t off = 0;
    float* x    = (float*)(ws + off); off += (size_t)N_NODES * 128 * 4;       // 10.24 MB
    float* emb  = (float*)(ws + off); off += N_SLOTS * 64 * 4;
    int*   cnt  = (int*)  (ws + off); off += N_SLOTS * 4;
    int*   gcnt = (int*)  (ws + off); off += 16;
    int2*  lst  = (int2*) (ws + off); off += (size_t)N_SLOTS * CAP * 8;
    int*   gl   = (int*)  (ws + off); off += (size_t)N_SLOTS * CAP * 4;
    float* tfu  = (float*)(ws + off); off += N_SLOTS * 128 * 4;
    float* qb   = (float*)(ws + off); off += N_SLOTS * 128 * 4;
    float* scb  = (float*)(ws + off); off += (size_t)N_SLOTS * CAP * 4 * 4;
    float* vbuf = (float*)(ws + off); off += (size_t)N_SLOTS * CAP * 128 * 4; // 8.4 MB
    float* WT   = (float*)(ws + off); off += (size_t)NMAT * MSTRIDE * 4;      // 1.2 MB

    k_tr<<<NMAT, 256, 0, stream>>>(inW, ftW, teW2, aiW, aoW, opW, o1W, o2W,
                                   l1W, l2W, WT, gcnt);
    k_in_proj2<<<N_NODES / 8, 128, 0, stream>>>(nf, WT, inb, x);
    k_prep<<<N_SLOTS, 256, 0, stream>>>(ei, tp, cnt, lst, gl, gcnt);

    for (int l = 0; l < 2; ++l) {
        const float* WT_ft = WT + (1 + l) * MSTRIDE;
        const float* WT_te2 = WT + (3 + l) * MSTRIDE;
        const float* WT_q = WT + (5 + 3 * l) * MSTRIDE;
        const float* WT_k = WT + (6 + 3 * l) * MSTRIDE;
        const float* WT_v = WT + (7 + 3 * l) * MSTRIDE;
        const float* WT_ao = WT + (11 + l) * MSTRIDE;
        const float* WT_op = WT + (13 + l) * MSTRIDE;
        const float* bq = aib + l * 384;
        k_q2<<<N_SLOTS / 8, 128, 0, stream>>>(x, tp, WT_ft, ftb + l * 128,
                                              WT_q, bq, tfu, qb, l);
        k_edge2<<<256, 128, 0, stream>>>(
            x, ts, lst, gl, gcnt, teW1 + l * 128, teb1 + l * 128,
            WT_ft, ftb + l * 128, WT_te2, teb2 + l * 128,
            WT_k, bq + 128, WT_v, bq + 256, qb, scb, vbuf, l);
        k_reduce2<<<N_SLOTS / 8, 128, 0, stream>>>(
            cnt, tp, scb, vbuf, tfu, WT_ao, aob + l * 128,
            WT_op, opb + l * 128, x,
            WT + 15 * MSTRIDE, o1b, WT + 17 * MSTRIDE, o2b, emb, l);
    }
    k_pair2<<<N_PAIRS / 8, 128, 0, stream>>>(emb, WT + 16 * MSTRIDE, l1b,
                                             WT + 18 * MSTRIDE, l2b, l3W, l3b, out);
}

// Round 5
// 264.208 us; speedup vs baseline: 1.7141x; 1.2268x over previous
//
#include <hip/hip_runtime.h>
#include <math.h>

#define N_NODES 20000
#define N_EDGES 50000
#define N_SLOTS 256   // N_PAIRS * 2 flattened targets
#define N_PAIRS 128
#define CAP 64        // max incident edges per slot (deg ~ Poisson(5))
#define MSTRIDE 16384 // floats per transposed-matrix slot in ws
#define NMAT 19

// ---------- helpers ----------
__device__ __forceinline__ float4 relu4(float4 v) {
    return make_float4(fmaxf(v.x, 0.f), fmaxf(v.y, 0.f), fmaxf(v.z, 0.f), fmaxf(v.w, 0.f));
}
__device__ __forceinline__ float4 add4(float4 a, float4 b) {
    return make_float4(a.x + b.x, a.y + b.y, a.z + b.z, a.w + b.w);
}
__device__ __forceinline__ void fma4(float4& acc, const float4 w, const float s) {
    acc.x = fmaf(w.x, s, acc.x); acc.y = fmaf(w.y, s, acc.y);
    acc.z = fmaf(w.z, s, acc.z); acc.w = fmaf(w.w, s, acc.w);
}
#define F4Z make_float4(0.f, 0.f, 0.f, 0.f)

// --- K-split matvec family: group g covers k in [32g, 32g+32); each weight
// matrix is read ONCE per block (vs 4x for item-split). Partials combined via LDS.
__device__ __forceinline__ void mv_ks8(const float* __restrict__ WT,
                                       const float* __restrict__ xs,
                                       int g, int jj, float4* acc) {
    const float4* W4 = (const float4*)WT;
    const float4* x4 = (const float4*)xs;
#pragma unroll 2
    for (int kk4 = 0; kk4 < 8; ++kk4) {
        int k4 = g * 8 + kk4;
        float4 w0 = W4[(k4 * 4 + 0) * 32 + jj];
        float4 w1 = W4[(k4 * 4 + 1) * 32 + jj];
        float4 w2 = W4[(k4 * 4 + 2) * 32 + jj];
        float4 w3 = W4[(k4 * 4 + 3) * 32 + jj];
#pragma unroll
        for (int e = 0; e < 8; ++e) {
            float4 xv = x4[e * 32 + k4];
            fma4(acc[e], w0, xv.x); fma4(acc[e], w1, xv.y);
            fma4(acc[e], w2, xv.z); fma4(acc[e], w3, xv.w);
        }
    }
}

__device__ __forceinline__ float4 mv_ks1(const float* __restrict__ WT,
                                         const float* __restrict__ xv128,
                                         int g, int jj) {
    const float4* W4 = (const float4*)WT;
    const float4* x4 = (const float4*)xv128;
    float4 acc = F4Z;
#pragma unroll 2
    for (int kk4 = 0; kk4 < 8; ++kk4) {
        int k4 = g * 8 + kk4;
        float4 xv = x4[k4];
        fma4(acc, W4[(k4 * 4 + 0) * 32 + jj], xv.x);
        fma4(acc, W4[(k4 * 4 + 1) * 32 + jj], xv.y);
        fma4(acc, W4[(k4 * 4 + 2) * 32 + jj], xv.z);
        fma4(acc, W4[(k4 * 4 + 3) * 32 + jj], xv.w);
    }
    return acc;
}

__device__ __forceinline__ float4 comb8(const float4* pb, int it, int jj) {
    return add4(add4(pb[it * 32 + jj], pb[(8 + it) * 32 + jj]),
                add4(pb[(16 + it) * 32 + jj], pb[(24 + it) * 32 + jj]));
}
__device__ __forceinline__ float4 comb1(const float4* pb, int jj) {
    return add4(add4(pb[jj], pb[32 + jj]), add4(pb[64 + jj], pb[96 + jj]));
}

// --- item-split matvec (used only in the 32-block reduce kernel) ---
template<int EPG>
__device__ __forceinline__ void mvT1(const float* __restrict__ WT,
                                     const float* __restrict__ xs,
                                     int g, int jj, float4* acc) {
    const float4* W4 = (const float4*)WT;
    const float4* x4 = (const float4*)xs;
#pragma unroll 2
    for (int k4 = 0; k4 < 32; ++k4) {
        float4 w0 = W4[(k4 * 4 + 0) * 32 + jj];
        float4 w1 = W4[(k4 * 4 + 1) * 32 + jj];
        float4 w2 = W4[(k4 * 4 + 2) * 32 + jj];
        float4 w3 = W4[(k4 * 4 + 3) * 32 + jj];
#pragma unroll
        for (int e = 0; e < EPG; ++e) {
            float4 xv = x4[(g * EPG + e) * 32 + k4];
            fma4(acc[e], w0, xv.x); fma4(acc[e], w1, xv.y);
            fma4(acc[e], w2, xv.z); fma4(acc[e], w3, xv.w);
        }
    }
}

template<int EPG>
__device__ __forceinline__ void mvT1_64(const float* __restrict__ WT,
                                        const float* __restrict__ xs,
                                        int g, int jj, float4* acc) {
    const float4* W4 = (const float4*)WT;
    const float4* x4 = (const float4*)xs;
    int j16 = jj & 15;
#pragma unroll 2
    for (int k4 = 0; k4 < 32; ++k4) {
        float4 w0 = W4[(k4 * 4 + 0) * 16 + j16];
        float4 w1 = W4[(k4 * 4 + 1) * 16 + j16];
        float4 w2 = W4[(k4 * 4 + 2) * 16 + j16];
        float4 w3 = W4[(k4 * 4 + 3) * 16 + j16];
#pragma unroll
        for (int e = 0; e < EPG; ++e) {
            float4 xv = x4[(g * EPG + e) * 32 + k4];
            fma4(acc[e], w0, xv.x); fma4(acc[e], w1, xv.y);
            fma4(acc[e], w2, xv.z); fma4(acc[e], w3, xv.w);
        }
    }
}

// ---------- kernels ----------

// fused: weight transpose (blocks 0..71, 32-row chunks) + per-slot edge scan (all 256)
__global__ __launch_bounds__(256) void k_prep_tr(
    const int* __restrict__ ei, const int* __restrict__ tp,
    const float* __restrict__ inW, const float* __restrict__ ftW,
    const float* __restrict__ teW2, const float* __restrict__ aiW,
    const float* __restrict__ aoW, const float* __restrict__ opW,
    const float* __restrict__ o1W, const float* __restrict__ o2W,
    const float* __restrict__ l1W, const float* __restrict__ l2W,
    float* __restrict__ WT, int* __restrict__ cnt, int2* __restrict__ lst) {
    __shared__ float tile[32][129];
    __shared__ int lc;
    const int b = blockIdx.x;
    if (threadIdx.x == 0) lc = 0;
    if (b < 72) {  // block-uniform branch: barriers inside are legal
        int m, r0, rows;
        if (b < 68) { m = b >> 2; r0 = (b & 3) * 32; rows = 128; }
        else { int mm = b - 68; m = 17 + (mm >> 1); r0 = (mm & 1) * 32; rows = 64; }
        const float* src;
        if (m == 0) src = inW;
        else if (m <= 2) src = ftW + (m - 1) * MSTRIDE;
        else if (m <= 4) src = teW2 + (m - 3) * MSTRIDE;
        else if (m <= 10) src = aiW + (m - 5) * MSTRIDE;  // q0,k0,v0,q1,k1,v1
        else if (m <= 12) src = aoW + (m - 11) * MSTRIDE;
        else if (m <= 14) src = opW + (m - 13) * MSTRIDE;
        else if (m == 15) src = o1W;
        else if (m == 16) src = l1W;
        else if (m == 17) src = o2W;
        else src = l2W;
        float* dst = WT + m * MSTRIDE;
        for (int idx = threadIdx.x; idx < 32 * 128; idx += 256) {
            int r = idx >> 7, c = idx & 127;
            tile[r][c] = src[(r0 + r) * 128 + c];
        }
        __syncthreads();
        for (int idx = threadIdx.x; idx < 128 * 32; idx += 256) {
            int k = idx >> 5, jr = idx & 31;
            dst[k * rows + r0 + jr] = tile[jr][k];
        }
    }
    __syncthreads();
    // per-slot incident-edge scan
    const int u = tp[b];
    const int4* src4 = (const int4*)ei;
    const int4* dst4 = (const int4*)(ei + N_EDGES);
    for (int e4 = threadIdx.x; e4 < N_EDGES / 4; e4 += 256) {
        int4 s = src4[e4];
        int4 d = dst4[e4];
        int ss[4] = {s.x, s.y, s.z, s.w};
        int dd[4] = {d.x, d.y, d.z, d.w};
#pragma unroll
        for (int t = 0; t < 4; ++t) {
            if (ss[t] == u || dd[t] == u) {
                int nbr = (ss[t] == u) ? dd[t] : ss[t];
                int pos = atomicAdd(&lc, 1);
                if (pos < CAP) lst[b * CAP + pos] = make_int2(e4 * 4 + t, nbr);
            }
        }
    }
    __syncthreads();
    if (threadIdx.x == 0) cnt[b] = lc;
}

// one block per slot: x0_u, tf_u, q (phase A) then batches of 8 edges:
// x0_nbr (layer 0 only, also written to x for layer 1), z, k, v, scores, vbuf.
__global__ __launch_bounds__(128) void k_edge(
    const float* __restrict__ nf, const float* __restrict__ x,
    const float* __restrict__ ts, const int* __restrict__ tp,
    const int* __restrict__ cnt, const int2* __restrict__ lst,
    const float* __restrict__ WT_in, const float* __restrict__ inb,
    const float* __restrict__ WT_ft, const float* __restrict__ ftb,
    const float* __restrict__ teW1, const float* __restrict__ teb1,
    const float* __restrict__ WT_te2, const float* __restrict__ teb2,
    const float* __restrict__ WT_q, const float* __restrict__ bq,
    const float* __restrict__ WT_k, const float* __restrict__ bk,
    const float* __restrict__ WT_v, const float* __restrict__ bv,
    float* __restrict__ x_out, float* __restrict__ tfu_g,
    float* __restrict__ scores, float* __restrict__ vbuf, int layer) {
    __shared__ __align__(16) float xu[128], x0u[128], tfv[128], qv[128];
    __shared__ __align__(16) float xs[8 * 128], t1s[8 * 128], x0s[8 * 128], zs[8 * 128];
    __shared__ __align__(16) float4 pbA[4 * 8 * 32], pbB[4 * 8 * 32];
    __shared__ int nbr_s[8];
    __shared__ float ts_s[8];
    const int slot = blockIdx.x, tid = threadIdx.x, g = tid >> 5, jj = tid & 31;
    const float scale = 0.17677669529663687f;  // 1/sqrt(32)
    const int u = tp[slot];
    const int c = min(cnt[slot], CAP);

    // ---- phase A: per-slot x0_u (layer 0), tf_u, q ----
    xu[tid] = (layer == 0) ? nf[(size_t)u * 128 + tid] : x[(size_t)u * 128 + tid];
    __syncthreads();
    const float* xeff = xu;
    if (layer == 0) {
        pbA[g * 32 + jj] = mv_ks1(WT_in, xu, g, jj);
        __syncthreads();
        float4 s = add4(comb1(pbA, jj), *(const float4*)(inb + jj * 4));
        *(float4*)(x0u + jj * 4) = s;  // all groups write identical value
        xeff = x0u;
        __syncthreads();
    }
    pbA[g * 32 + jj] = mv_ks1(WT_ft, xeff, g, jj);
    __syncthreads();
    {
        float4 t = add4(comb1(pbA, jj), *(const float4*)(ftb + jj * 4));
        *(float4*)(tfv + jj * 4) = t;
        if (g == 0) *(float4*)(tfu_g + (size_t)slot * 128 + jj * 4) = t;
    }
    __syncthreads();
    pbA[g * 32 + jj] = mv_ks1(WT_q, tfv, g, jj);
    __syncthreads();
    *(float4*)(qv + jj * 4) = add4(comb1(pbA, jj), *(const float4*)(bq + jj * 4));
    __syncthreads();

    // ---- phase B: edge batches of 8 ----
    for (int base = 0; base < c; base += 8) {
        if (tid < 8) {
            int i = base + tid;
            int2 en = (i < c) ? lst[slot * CAP + i] : make_int2(0, 0);
            nbr_s[tid] = en.y;
            ts_s[tid] = (i < c) ? ts[en.x] : 0.f;
        }
        __syncthreads();
        {   // stage neighbor features + time-encoding layer 1
            int e = tid >> 4, c0 = (tid & 15) * 8;
            const float* srcp = (layer == 0) ? (nf + (size_t)nbr_s[e] * 128 + c0)
                                             : (x + (size_t)nbr_s[e] * 128 + c0);
            float4 v0 = *(const float4*)srcp, v1 = *(const float4*)(srcp + 4);
            float* dstp = (layer == 0) ? xs : x0s;
            *(float4*)(dstp + e * 128 + c0) = v0;
            *(float4*)(dstp + e * 128 + c0 + 4) = v1;
            float tse = ts_s[e];
            float4 w0 = *(const float4*)(teW1 + c0);
            float4 w1 = *(const float4*)(teW1 + c0 + 4);
            float4 b0 = *(const float4*)(teb1 + c0);
            float4 b1 = *(const float4*)(teb1 + c0 + 4);
            float4 t0 = make_float4(fmaxf(fmaf(tse, w0.x, b0.x), 0.f),
                                    fmaxf(fmaf(tse, w0.y, b0.y), 0.f),
                                    fmaxf(fmaf(tse, w0.z, b0.z), 0.f),
                                    fmaxf(fmaf(tse, w0.w, b0.w), 0.f));
            float4 t1 = make_float4(fmaxf(fmaf(tse, w1.x, b1.x), 0.f),
                                    fmaxf(fmaf(tse, w1.y, b1.y), 0.f),
                                    fmaxf(fmaf(tse, w1.z, b1.z), 0.f),
                                    fmaxf(fmaf(tse, w1.w, b1.w), 0.f));
            *(float4*)(t1s + e * 128 + c0) = t0;
            *(float4*)(t1s + e * 128 + c0 + 4) = t1;
        }
        __syncthreads();
        if (layer == 0) {  // x0_nbr = inW @ nf[nbr] + inb; store relu(x0) for layer 1
            float4 acc[8] = {F4Z, F4Z, F4Z, F4Z, F4Z, F4Z, F4Z, F4Z};
            mv_ks8(WT_in, xs, g, jj, acc);
#pragma unroll
            for (int e = 0; e < 8; ++e) pbA[(g * 8 + e) * 32 + jj] = acc[e];
            __syncthreads();
            float4 ib4 = *(const float4*)(inb + jj * 4);
#pragma unroll
            for (int r = 0; r < 2; ++r) {
                int it = g * 2 + r;
                float4 x0v = add4(comb8(pbA, it, jj), ib4);
                *(float4*)(x0s + it * 128 + jj * 4) = x0v;
                if (base + it < c)
                    *(float4*)(x_out + (size_t)nbr_s[it] * 128 + jj * 4) = relu4(x0v);
            }
            __syncthreads();
        }
        {   // z = ftW@x0 + ftb + teW2@t1 + teb2
            float4 acc[8] = {F4Z, F4Z, F4Z, F4Z, F4Z, F4Z, F4Z, F4Z};
            mv_ks8(WT_ft, x0s, g, jj, acc);
#pragma unroll
            for (int e = 0; e < 8; ++e) pbA[(g * 8 + e) * 32 + jj] = acc[e];
            float4 acc2[8] = {F4Z, F4Z, F4Z, F4Z, F4Z, F4Z, F4Z, F4Z};
            mv_ks8(WT_te2, t1s, g, jj, acc2);
#pragma unroll
            for (int e = 0; e < 8; ++e) pbB[(g * 8 + e) * 32 + jj] = acc2[e];
            __syncthreads();
            float4 fb = *(const float4*)(ftb + jj * 4);
            float4 tb = *(const float4*)(teb2 + jj * 4);
#pragma unroll
            for (int r = 0; r < 2; ++r) {
                int it = g * 2 + r;
                float4 z4 = add4(add4(comb8(pbA, it, jj), comb8(pbB, it, jj)), add4(fb, tb));
                *(float4*)(zs + it * 128 + jj * 4) = z4;
            }
            __syncthreads();
        }
        {   // k, v, score
            float4 acc[8] = {F4Z, F4Z, F4Z, F4Z, F4Z, F4Z, F4Z, F4Z};
            mv_ks8(WT_k, zs, g, jj, acc);
#pragma unroll
            for (int e = 0; e < 8; ++e) pbA[(g * 8 + e) * 32 + jj] = acc[e];
            float4 acc2[8] = {F4Z, F4Z, F4Z, F4Z, F4Z, F4Z, F4Z, F4Z};
            mv_ks8(WT_v, zs, g, jj, acc2);
#pragma unroll
            for (int e = 0; e < 8; ++e) pbB[(g * 8 + e) * 32 + jj] = acc2[e];
            __syncthreads();
            float4 bk4 = *(const float4*)(bk + jj * 4);
            float4 bv4 = *(const float4*)(bv + jj * 4);
            float4 q4 = *(const float4*)(qv + jj * 4);
#pragma unroll
            for (int r = 0; r < 2; ++r) {
                int it = g * 2 + r;
                float4 kk = add4(comb8(pbA, it, jj), bk4);
                float4 vv = add4(comb8(pbB, it, jj), bv4);
                float pr = q4.x * kk.x + q4.y * kk.y + q4.z * kk.z + q4.w * kk.w;
                pr += __shfl_xor(pr, 1);
                pr += __shfl_xor(pr, 2);
                pr += __shfl_xor(pr, 4);  // sum over the 8 lanes of head jj>>3
                if (base + it < c) {
                    int pos = slot * CAP + base + it;
                    if ((jj & 7) == 0) scores[pos * 4 + (jj >> 3)] = pr * scale;
                    *(float4*)(vbuf + (size_t)pos * 128 + jj * 4) = vv;
                }
            }
            __syncthreads();  // before next batch restages LDS
        }
    }
}

// 8 slots per block: softmax + attn_out + op; mode 0: scatter relu(agg) into x;
// mode 1: emb head then the FUSED pair head (this block's 8 slots = 4 pairs).
__global__ __launch_bounds__(128) void k_reduce(
    const int* __restrict__ cnt, const int* __restrict__ tp,
    const float* __restrict__ scores, const float* __restrict__ vbuf,
    const float* __restrict__ tfu_g,
    const float* __restrict__ WT_ao, const float* __restrict__ aob,
    const float* __restrict__ WT_op, const float* __restrict__ opb,
    float* __restrict__ x,
    const float* __restrict__ WT_o1, const float* __restrict__ o1b,
    const float* __restrict__ WT_o2, const float* __restrict__ o2b,
    const float* __restrict__ WT_l1, const float* __restrict__ l1b,
    const float* __restrict__ WT_l2, const float* __restrict__ l2b,
    const float* __restrict__ l3W, const float* __restrict__ l3b,
    float* __restrict__ out, int mode) {
    __shared__ __align__(16) float outvs[8 * 128], zs[8 * 128], embs[8 * 64], z2s[4 * 64];
    __shared__ int u_s[8], c_s[8];
    const int tid = threadIdx.x, g = tid >> 5, jj = tid & 31;
    const int base = blockIdx.x * 8;
    if (tid < 8) {
        u_s[tid] = tp[base + tid];
        c_s[tid] = min(cnt[base + tid], CAP);
    }
    __syncthreads();
    const int j = tid, h = j >> 5;
    for (int e = 0; e < 8; ++e) {
        int slot = base + e, c = c_s[e];
        if (c > 0) {
            float m = -INFINITY;
            for (int i = 0; i < c; ++i) m = fmaxf(m, scores[(slot * CAP + i) * 4 + h]);
            float l = 0.f, o = 0.f;
            for (int i = 0; i < c; ++i) {
                float p = __expf(scores[(slot * CAP + i) * 4 + h] - m);
                l += p;
                o = fmaf(p, vbuf[(size_t)(slot * CAP + i) * 128 + j], o);
            }
            outvs[e * 128 + j] = o / l;
        } else {
            outvs[e * 128 + j] = 0.f;
        }
    }
    __syncthreads();
    float4 acc[2] = {F4Z, F4Z};
    mvT1<2>(WT_ao, outvs, g, jj, acc);
    float4 ab = *(const float4*)(aob + jj * 4);
#pragma unroll
    for (int e = 0; e < 2; ++e) {
        int eg = g * 2 + e;
        float4 z4;
        if (c_s[eg] > 0) z4 = add4(acc[e], ab);
        else z4 = *(const float4*)(tfu_g + (size_t)(base + eg) * 128 + jj * 4);
        *(float4*)(zs + eg * 128 + jj * 4) = z4;
    }
    __syncthreads();
    float4 acc2[2] = {F4Z, F4Z};
    mvT1<2>(WT_op, zs, g, jj, acc2);
    float4 ob = *(const float4*)(opb + jj * 4);
    if (mode == 0) {
#pragma unroll
        for (int e = 0; e < 2; ++e) {
            int eg = g * 2 + e;
            *(float4*)(x + (size_t)u_s[eg] * 128 + jj * 4) = relu4(add4(acc2[e], ob));
        }
        return;
    }
    // mode 1: emb head
    __syncthreads();
#pragma unroll
    for (int e = 0; e < 2; ++e) {
        int eg = g * 2 + e;
        *(float4*)(outvs + eg * 128 + jj * 4) = relu4(add4(acc2[e], ob));
    }
    __syncthreads();
    float4 acc3[2] = {F4Z, F4Z};
    mvT1<2>(WT_o1, outvs, g, jj, acc3);
    float4 b1 = *(const float4*)(o1b + jj * 4);
#pragma unroll
    for (int e = 0; e < 2; ++e) {
        int eg = g * 2 + e;
        *(float4*)(zs + eg * 128 + jj * 4) = relu4(add4(acc3[e], b1));
    }
    __syncthreads();
    float4 acc4[2] = {F4Z, F4Z};
    mvT1_64<2>(WT_o2, zs, g, jj, acc4);
    if (jj < 16) {
        float4 b2 = *(const float4*)(o2b + jj * 4);
#pragma unroll
        for (int e = 0; e < 2; ++e) {
            int eg = g * 2 + e;
            *(float4*)(embs + eg * 64 + jj * 4) = add4(acc4[e], b2);
        }
    }
    __syncthreads();
    // fused pair head: local pair g uses emb rows 2g,2g+1 = embs[g*128..g*128+127]
    {
        float4 a1[1] = {F4Z};
        mvT1<1>(WT_l1, embs, g, jj, a1);
        float4 lb1 = *(const float4*)(l1b + jj * 4);
        *(float4*)(zs + g * 128 + jj * 4) = relu4(add4(a1[0], lb1));
    }
    __syncthreads();
    {
        float4 a2[1] = {F4Z};
        mvT1_64<1>(WT_l2, zs, g, jj, a2);
        if (jj < 16) {
            float4 lb2 = *(const float4*)(l2b + jj * 4);
            *(float4*)(z2s + g * 64 + jj * 4) = relu4(add4(a2[0], lb2));
        }
    }
    __syncthreads();
    if (tid < 4) {
        float s = l3b[0];
#pragma unroll 8
        for (int k = 0; k < 64; ++k) s = fmaf(l3W[k], z2s[tid * 64 + k], s);
        out[blockIdx.x * 4 + tid] = 1.f / (1.f + __expf(-s));
    }
}

// ---------- launch ----------
extern "C" void kernel_launch(void* const* d_in, const int* in_sizes, int n_in,
                              void* d_out, int out_size, void* d_ws, size_t ws_size,
                              hipStream_t stream) {
    const float* nf  = (const float*)d_in[0];
    const int*   ei  = (const int*)d_in[1];
    const float* ts  = (const float*)d_in[2];
    const int*   tp  = (const int*)d_in[3];
    const float* inW = (const float*)d_in[4];
    const float* inb = (const float*)d_in[5];
    const float* teW1 = (const float*)d_in[6];
    const float* teb1 = (const float*)d_in[7];
    const float* teW2 = (const float*)d_in[8];
    const float* teb2 = (const float*)d_in[9];
    const float* aiW = (const float*)d_in[10];
    const float* aib = (const float*)d_in[11];
    const float* aoW = (const float*)d_in[12];
    const float* aob = (const float*)d_in[13];
    const float* ftW = (const float*)d_in[14];
    const float* ftb = (const float*)d_in[15];
    const float* opW = (const float*)d_in[16];
    const float* opb = (const float*)d_in[17];
    const float* o1W = (const float*)d_in[18];
    const float* o1b = (const float*)d_in[19];
    const float* o2W = (const float*)d_in[20];
    const float* o2b = (const float*)d_in[21];
    const float* l1W = (const float*)d_in[22];
    const float* l1b = (const float*)d_in[23];
    const float* l2W = (const float*)d_in[24];
    const float* l2b = (const float*)d_in[25];
    const float* l3W = (const float*)d_in[26];
    const float* l3b = (const float*)d_in[27];
    float* out = (float*)d_out;

    char* ws = (char*)d_ws;
    size_t off = 0;
    float* x    = (float*)(ws + off); off += (size_t)N_NODES * 128 * 4;       // 10.24 MB
    int*   cnt  = (int*)  (ws + off); off += N_SLOTS * 4;
    int2*  lst  = (int2*) (ws + off); off += (size_t)N_SLOTS * CAP * 8;
    float* tfu  = (float*)(ws + off); off += N_SLOTS * 128 * 4;
    float* scb  = (float*)(ws + off); off += (size_t)N_SLOTS * CAP * 4 * 4;
    float* vbuf = (float*)(ws + off); off += (size_t)N_SLOTS * CAP * 128 * 4; // 8.4 MB
    float* WT   = (float*)(ws + off); off += (size_t)NMAT * MSTRIDE * 4;      // 1.2 MB

    k_prep_tr<<<N_SLOTS, 256, 0, stream>>>(ei, tp, inW, ftW, teW2, aiW, aoW, opW,
                                           o1W, o2W, l1W, l2W, WT, cnt, lst);

    for (int l = 0; l < 2; ++l) {
        const float* WT_ft = WT + (1 + l) * MSTRIDE;
        const float* WT_te2 = WT + (3 + l) * MSTRIDE;
        const float* WT_q = WT + (5 + 3 * l) * MSTRIDE;
        const float* WT_k = WT + (6 + 3 * l) * MSTRIDE;
        const float* WT_v = WT + (7 + 3 * l) * MSTRIDE;
        const float* WT_ao = WT + (11 + l) * MSTRIDE;
        const float* WT_op = WT + (13 + l) * MSTRIDE;
        const float* bq = aib + l * 384;
        k_edge<<<N_SLOTS, 128, 0, stream>>>(
            nf, x, ts, tp, cnt, lst,
            WT, inb, WT_ft, ftb + l * 128, teW1 + l * 128, teb1 + l * 128,
            WT_te2, teb2 + l * 128, WT_q, bq, WT_k, bq + 128, WT_v, bq + 256,
            x, tfu, scb, vbuf, l);
        k_reduce<<<N_SLOTS / 8, 128, 0, stream>>>(
            cnt, tp, scb, vbuf, tfu, WT_ao, aob + l * 128,
            WT_op, opb + l * 128, x,
            WT + 15 * MSTRIDE, o1b, WT + 17 * MSTRIDE, o2b,
            WT + 16 * MSTRIDE, l1b, WT + 18 * MSTRIDE, l2b, l3W, l3b, out, l);
    }
}

// Round 6
// 205.109 us; speedup vs baseline: 2.2080x; 1.2881x over previous
//
#include <hip/hip_runtime.h>
#include <math.h>

#define N_NODES 20000
#define N_EDGES 50000
#define N_SLOTS 256   // N_PAIRS * 2 flattened targets
#define N_PAIRS 128
#define CAP 64        // max incident edges per slot (deg ~ Poisson(5))
#define MSTRIDE 16384 // floats per transposed-matrix slot in ws
#define NMAT 19

// ---------- helpers ----------
__device__ __forceinline__ float4 relu4(float4 v) {
    return make_float4(fmaxf(v.x, 0.f), fmaxf(v.y, 0.f), fmaxf(v.z, 0.f), fmaxf(v.w, 0.f));
}
__device__ __forceinline__ float4 add4(float4 a, float4 b) {
    return make_float4(a.x + b.x, a.y + b.y, a.z + b.z, a.w + b.w);
}
__device__ __forceinline__ void fma4(float4& acc, const float4 w, const float s) {
    acc.x = fmaf(w.x, s, acc.x); acc.y = fmaf(w.y, s, acc.y);
    acc.z = fmaf(w.z, s, acc.z); acc.w = fmaf(w.w, s, acc.w);
}
#define F4Z make_float4(0.f, 0.f, 0.f, 0.f)

// ===== 4-group K-split (128-thread kernels): group g covers k-chunks [8g,8g+8) =====
__device__ __forceinline__ float4 mv_ks1(const float* __restrict__ WT,
                                         const float* __restrict__ xv128,
                                         int g, int jj) {
    const float4* W4 = (const float4*)WT;
    const float4* x4 = (const float4*)xv128;
    float4 acc = F4Z;
#pragma unroll 2
    for (int kk4 = 0; kk4 < 8; ++kk4) {
        int k4 = g * 8 + kk4;
        float4 xv = x4[k4];
        fma4(acc, W4[(k4 * 4 + 0) * 32 + jj], xv.x);
        fma4(acc, W4[(k4 * 4 + 1) * 32 + jj], xv.y);
        fma4(acc, W4[(k4 * 4 + 2) * 32 + jj], xv.z);
        fma4(acc, W4[(k4 * 4 + 3) * 32 + jj], xv.w);
    }
    return acc;
}
// 64-output variant (WT stored [128][64]); lanes jj>=16 compute duplicates
__device__ __forceinline__ float4 mv_ks1_64(const float* __restrict__ WT,
                                            const float* __restrict__ xv128,
                                            int g, int jj) {
    const float4* W4 = (const float4*)WT;
    const float4* x4 = (const float4*)xv128;
    int j16 = jj & 15;
    float4 acc = F4Z;
#pragma unroll 2
    for (int kk4 = 0; kk4 < 8; ++kk4) {
        int k4 = g * 8 + kk4;
        float4 xv = x4[k4];
        fma4(acc, W4[(k4 * 4 + 0) * 16 + j16], xv.x);
        fma4(acc, W4[(k4 * 4 + 1) * 16 + j16], xv.y);
        fma4(acc, W4[(k4 * 4 + 2) * 16 + j16], xv.z);
        fma4(acc, W4[(k4 * 4 + 3) * 16 + j16], xv.w);
    }
    return acc;
}
__device__ __forceinline__ float4 comb1(const float4* pb, int jj) {
    return add4(add4(pb[jj], pb[32 + jj]), add4(pb[64 + jj], pb[96 + jj]));
}

// ===== 8-group K-split (256-thread k_edge): group g covers k-chunks [4g,4g+4) =====
__device__ __forceinline__ float4 mv_ks1_g8(const float* __restrict__ WT,
                                            const float* __restrict__ xv128,
                                            int g, int jj) {
    const float4* W4 = (const float4*)WT;
    const float4* x4 = (const float4*)xv128;
    float4 acc = F4Z;
#pragma unroll
    for (int kk4 = 0; kk4 < 4; ++kk4) {
        int k4 = g * 4 + kk4;
        float4 xv = x4[k4];
        fma4(acc, W4[(k4 * 4 + 0) * 32 + jj], xv.x);
        fma4(acc, W4[(k4 * 4 + 1) * 32 + jj], xv.y);
        fma4(acc, W4[(k4 * 4 + 2) * 32 + jj], xv.z);
        fma4(acc, W4[(k4 * 4 + 3) * 32 + jj], xv.w);
    }
    return acc;
}
__device__ __forceinline__ void mv8_g8(const float* __restrict__ WT,
                                       const float* __restrict__ xs,
                                       int g, int jj, float4* acc) {
    const float4* W4 = (const float4*)WT;
    const float4* x4 = (const float4*)xs;
#pragma unroll
    for (int kk4 = 0; kk4 < 4; ++kk4) {
        int k4 = g * 4 + kk4;
        float4 w0 = W4[(k4 * 4 + 0) * 32 + jj];
        float4 w1 = W4[(k4 * 4 + 1) * 32 + jj];
        float4 w2 = W4[(k4 * 4 + 2) * 32 + jj];
        float4 w3 = W4[(k4 * 4 + 3) * 32 + jj];
#pragma unroll
        for (int e = 0; e < 8; ++e) {
            float4 xv = x4[e * 32 + k4];
            fma4(acc[e], w0, xv.x); fma4(acc[e], w1, xv.y);
            fma4(acc[e], w2, xv.z); fma4(acc[e], w3, xv.w);
        }
    }
}
__device__ __forceinline__ float4 comb1_g8(const float4* pb, int jj) {
    float4 s = pb[jj];
#pragma unroll
    for (int gp = 1; gp < 8; ++gp) s = add4(s, pb[gp * 32 + jj]);
    return s;
}
__device__ __forceinline__ float4 comb8_g8(const float4* pb, int it, int jj) {
    float4 s = pb[it * 32 + jj];
#pragma unroll
    for (int gp = 1; gp < 8; ++gp) s = add4(s, pb[(gp * 8 + it) * 32 + jj]);
    return s;
}

// ---------- kernels ----------

// fused: weight transpose (blocks 0..71, 32-row chunks) + per-slot edge scan (all 256)
__global__ __launch_bounds__(256) void k_prep_tr(
    const int* __restrict__ ei, const int* __restrict__ tp,
    const float* __restrict__ inW, const float* __restrict__ ftW,
    const float* __restrict__ teW2, const float* __restrict__ aiW,
    const float* __restrict__ aoW, const float* __restrict__ opW,
    const float* __restrict__ o1W, const float* __restrict__ o2W,
    const float* __restrict__ l1W, const float* __restrict__ l2W,
    float* __restrict__ WT, int* __restrict__ cnt, int2* __restrict__ lst) {
    __shared__ float tile[32][129];
    __shared__ int lc;
    const int b = blockIdx.x;
    if (threadIdx.x == 0) lc = 0;
    if (b < 72) {  // block-uniform branch: barriers inside are legal
        int m, r0, rows;
        if (b < 68) { m = b >> 2; r0 = (b & 3) * 32; rows = 128; }
        else { int mm = b - 68; m = 17 + (mm >> 1); r0 = (mm & 1) * 32; rows = 64; }
        const float* src;
        if (m == 0) src = inW;
        else if (m <= 2) src = ftW + (m - 1) * MSTRIDE;
        else if (m <= 4) src = teW2 + (m - 3) * MSTRIDE;
        else if (m <= 10) src = aiW + (m - 5) * MSTRIDE;  // q0,k0,v0,q1,k1,v1
        else if (m <= 12) src = aoW + (m - 11) * MSTRIDE;
        else if (m <= 14) src = opW + (m - 13) * MSTRIDE;
        else if (m == 15) src = o1W;
        else if (m == 16) src = l1W;
        else if (m == 17) src = o2W;
        else src = l2W;
        float* dst = WT + m * MSTRIDE;
        for (int idx = threadIdx.x; idx < 32 * 128; idx += 256) {
            int r = idx >> 7, c = idx & 127;
            tile[r][c] = src[(r0 + r) * 128 + c];
        }
        __syncthreads();
        for (int idx = threadIdx.x; idx < 128 * 32; idx += 256) {
            int k = idx >> 5, jr = idx & 31;
            dst[k * rows + r0 + jr] = tile[jr][k];
        }
    }
    __syncthreads();
    // per-slot incident-edge scan
    const int u = tp[b];
    const int4* src4 = (const int4*)ei;
    const int4* dst4 = (const int4*)(ei + N_EDGES);
    for (int e4 = threadIdx.x; e4 < N_EDGES / 4; e4 += 256) {
        int4 s = src4[e4];
        int4 d = dst4[e4];
        int ss[4] = {s.x, s.y, s.z, s.w};
        int dd[4] = {d.x, d.y, d.z, d.w};
#pragma unroll
        for (int t = 0; t < 4; ++t) {
            if (ss[t] == u || dd[t] == u) {
                int nbr = (ss[t] == u) ? dd[t] : ss[t];
                int pos = atomicAdd(&lc, 1);
                if (pos < CAP) lst[b * CAP + pos] = make_int2(e4 * 4 + t, nbr);
            }
        }
    }
    __syncthreads();
    if (threadIdx.x == 0) cnt[b] = lc;
}

// one block (256 thr, 8 K-groups) per slot: phase A (x0_u, tf_u, q), then
// batches of 8 edges: x0_nbr (layer 0, also persisted), z, k, v, scores, vbuf.
__global__ __launch_bounds__(256) void k_edge(
    const float* __restrict__ nf, const float* __restrict__ x,
    const float* __restrict__ ts, const int* __restrict__ tp,
    const int* __restrict__ cnt, const int2* __restrict__ lst,
    const float* __restrict__ WT_in, const float* __restrict__ inb,
    const float* __restrict__ WT_ft, const float* __restrict__ ftb,
    const float* __restrict__ teW1, const float* __restrict__ teb1,
    const float* __restrict__ WT_te2, const float* __restrict__ teb2,
    const float* __restrict__ WT_q, const float* __restrict__ bq,
    const float* __restrict__ WT_k, const float* __restrict__ bk,
    const float* __restrict__ WT_v, const float* __restrict__ bv,
    float* __restrict__ x_out, float* __restrict__ tfu_g,
    float* __restrict__ scores, float* __restrict__ vbuf, int layer) {
    __shared__ __align__(16) float xu[128], x0u[128], tfv[128], qv[128];
    __shared__ __align__(16) float xs[8 * 128], t1s[8 * 128], x0s[8 * 128], zs[8 * 128];
    __shared__ __align__(16) float4 pb[8 * 8 * 32];  // 32 KB partial buffer
    __shared__ int nbr_s[8];
    __shared__ float ts_s[8];
    const int slot = blockIdx.x, tid = threadIdx.x, g = tid >> 5, jj = tid & 31;
    const float scale = 0.17677669529663687f;  // 1/sqrt(32)
    const int u = tp[slot];
    const int c = min(cnt[slot], CAP);

    // ---- phase A ----
    if (tid < 128) xu[tid] = (layer == 0) ? nf[(size_t)u * 128 + tid]
                                          : x[(size_t)u * 128 + tid];
    __syncthreads();
    const float* xeff = xu;
    if (layer == 0) {
        pb[g * 32 + jj] = mv_ks1_g8(WT_in, xu, g, jj);
        __syncthreads();
        if (g == 0)
            *(float4*)(x0u + jj * 4) = add4(comb1_g8(pb, jj), *(const float4*)(inb + jj * 4));
        xeff = x0u;
        __syncthreads();
    }
    pb[g * 32 + jj] = mv_ks1_g8(WT_ft, xeff, g, jj);
    __syncthreads();
    if (g == 0) {
        float4 t = add4(comb1_g8(pb, jj), *(const float4*)(ftb + jj * 4));
        *(float4*)(tfv + jj * 4) = t;
        *(float4*)(tfu_g + (size_t)slot * 128 + jj * 4) = t;
    }
    __syncthreads();
    pb[g * 32 + jj] = mv_ks1_g8(WT_q, tfv, g, jj);
    __syncthreads();
    if (g == 0)
        *(float4*)(qv + jj * 4) = add4(comb1_g8(pb, jj), *(const float4*)(bq + jj * 4));
    __syncthreads();

    // ---- phase B: edge batches of 8 (item it == group g) ----
    for (int base = 0; base < c; base += 8) {
        if (tid < 8) {
            int i = base + tid;
            int2 en = (i < c) ? lst[slot * CAP + i] : make_int2(0, 0);
            nbr_s[tid] = en.y;
            ts_s[tid] = (i < c) ? ts[en.x] : 0.f;
        }
        __syncthreads();
        {   // stage neighbor row + time-encoding layer-1 activation
            int e = tid >> 5, c0 = jj * 4;
            const float* srcp = (layer == 0) ? (nf + (size_t)nbr_s[e] * 128 + c0)
                                             : (x + (size_t)nbr_s[e] * 128 + c0);
            float4 v = *(const float4*)srcp;
            float* dstp = (layer == 0) ? xs : x0s;
            *(float4*)(dstp + e * 128 + c0) = v;
            float tse = ts_s[e];
            float4 w = *(const float4*)(teW1 + c0);
            float4 b = *(const float4*)(teb1 + c0);
            *(float4*)(t1s + e * 128 + c0) =
                make_float4(fmaxf(fmaf(tse, w.x, b.x), 0.f),
                            fmaxf(fmaf(tse, w.y, b.y), 0.f),
                            fmaxf(fmaf(tse, w.z, b.z), 0.f),
                            fmaxf(fmaf(tse, w.w, b.w), 0.f));
        }
        __syncthreads();
        if (layer == 0) {  // x0_nbr = inW @ nf[nbr] + inb; persist relu(x0)
            float4 acc[8] = {F4Z, F4Z, F4Z, F4Z, F4Z, F4Z, F4Z, F4Z};
            mv8_g8(WT_in, xs, g, jj, acc);
#pragma unroll
            for (int e = 0; e < 8; ++e) pb[(g * 8 + e) * 32 + jj] = acc[e];
            __syncthreads();
            {
                float4 x0v = add4(comb8_g8(pb, g, jj), *(const float4*)(inb + jj * 4));
                *(float4*)(x0s + g * 128 + jj * 4) = x0v;
                if (base + g < c)
                    *(float4*)(x_out + (size_t)nbr_s[g] * 128 + jj * 4) = relu4(x0v);
            }
            __syncthreads();
        }
        float4 za, zb;
        {   // z = ftW@x0 + ftb + teW2@t1 + teb2
            float4 acc[8] = {F4Z, F4Z, F4Z, F4Z, F4Z, F4Z, F4Z, F4Z};
            mv8_g8(WT_ft, x0s, g, jj, acc);
#pragma unroll
            for (int e = 0; e < 8; ++e) pb[(g * 8 + e) * 32 + jj] = acc[e];
            __syncthreads();
            za = comb8_g8(pb, g, jj);
            __syncthreads();
            float4 acc2[8] = {F4Z, F4Z, F4Z, F4Z, F4Z, F4Z, F4Z, F4Z};
            mv8_g8(WT_te2, t1s, g, jj, acc2);
#pragma unroll
            for (int e = 0; e < 8; ++e) pb[(g * 8 + e) * 32 + jj] = acc2[e];
            __syncthreads();
            zb = comb8_g8(pb, g, jj);
            float4 z4 = add4(add4(za, zb),
                             add4(*(const float4*)(ftb + jj * 4),
                                  *(const float4*)(teb2 + jj * 4)));
            *(float4*)(zs + g * 128 + jj * 4) = z4;
            __syncthreads();
        }
        {   // k, v, score
            float4 acc[8] = {F4Z, F4Z, F4Z, F4Z, F4Z, F4Z, F4Z, F4Z};
            mv8_g8(WT_k, zs, g, jj, acc);
#pragma unroll
            for (int e = 0; e < 8; ++e) pb[(g * 8 + e) * 32 + jj] = acc[e];
            __syncthreads();
            float4 kk = add4(comb8_g8(pb, g, jj), *(const float4*)(bk + jj * 4));
            __syncthreads();
            float4 acc2[8] = {F4Z, F4Z, F4Z, F4Z, F4Z, F4Z, F4Z, F4Z};
            mv8_g8(WT_v, zs, g, jj, acc2);
#pragma unroll
            for (int e = 0; e < 8; ++e) pb[(g * 8 + e) * 32 + jj] = acc2[e];
            __syncthreads();
            float4 vv = add4(comb8_g8(pb, g, jj), *(const float4*)(bv + jj * 4));
            float4 q4 = *(const float4*)(qv + jj * 4);
            float pr = q4.x * kk.x + q4.y * kk.y + q4.z * kk.z + q4.w * kk.w;
            pr += __shfl_xor(pr, 1);
            pr += __shfl_xor(pr, 2);
            pr += __shfl_xor(pr, 4);  // sum over the 8 lanes of head jj>>3
            if (base + g < c) {
                int pos = slot * CAP + base + g;
                if ((jj & 7) == 0) scores[pos * 4 + (jj >> 3)] = pr * scale;
                *(float4*)(vbuf + (size_t)pos * 128 + jj * 4) = vv;
            }
            __syncthreads();  // before next batch restages LDS
        }
    }
}

// one block per slot: softmax + attn_out + op; mode 0: scatter relu(agg) into x;
// mode 1: emb head -> emb[slot].
__global__ __launch_bounds__(128) void k_reduce(
    const int* __restrict__ cnt, const int* __restrict__ tp,
    const float* __restrict__ scores, const float* __restrict__ vbuf,
    const float* __restrict__ tfu_g,
    const float* __restrict__ WT_ao, const float* __restrict__ aob,
    const float* __restrict__ WT_op, const float* __restrict__ opb,
    float* __restrict__ x,
    const float* __restrict__ WT_o1, const float* __restrict__ o1b,
    const float* __restrict__ WT_o2, const float* __restrict__ o2b,
    float* __restrict__ emb, int mode) {
    __shared__ __align__(16) float outv[128], zv[128], xt[128], e1[128];
    __shared__ __align__(16) float4 pb[4 * 32];
    const int slot = blockIdx.x, tid = threadIdx.x, g = tid >> 5, jj = tid & 31;
    const int j = tid, h = j >> 5;
    const int u = tp[slot];
    const int c = min(cnt[slot], CAP);
    if (c > 0) {
        float m = -INFINITY;
        for (int i = 0; i < c; ++i) m = fmaxf(m, scores[(slot * CAP + i) * 4 + h]);
        float l = 0.f, o = 0.f;
        for (int i = 0; i < c; ++i) {
            float p = __expf(scores[(slot * CAP + i) * 4 + h] - m);
            l += p;
            o = fmaf(p, vbuf[(size_t)(slot * CAP + i) * 128 + j], o);
        }
        outv[j] = o / l;
    } else {
        outv[j] = 0.f;
    }
    __syncthreads();
    pb[g * 32 + jj] = mv_ks1(WT_ao, outv, g, jj);
    __syncthreads();
    if (g == 0) {
        float4 z4;
        if (c > 0) z4 = add4(comb1(pb, jj), *(const float4*)(aob + jj * 4));
        else z4 = *(const float4*)(tfu_g + (size_t)slot * 128 + jj * 4);
        *(float4*)(zv + jj * 4) = z4;
    }
    __syncthreads();
    pb[g * 32 + jj] = mv_ks1(WT_op, zv, g, jj);
    __syncthreads();
    if (mode == 0) {
        if (g == 0) {
            float4 a = relu4(add4(comb1(pb, jj), *(const float4*)(opb + jj * 4)));
            *(float4*)(x + (size_t)u * 128 + jj * 4) = a;
        }
        return;
    }
    if (g == 0)
        *(float4*)(xt + jj * 4) = relu4(add4(comb1(pb, jj), *(const float4*)(opb + jj * 4)));
    __syncthreads();
    pb[g * 32 + jj] = mv_ks1(WT_o1, xt, g, jj);
    __syncthreads();
    if (g == 0)
        *(float4*)(e1 + jj * 4) = relu4(add4(comb1(pb, jj), *(const float4*)(o1b + jj * 4)));
    __syncthreads();
    pb[g * 32 + jj] = mv_ks1_64(WT_o2, e1, g, jj);
    __syncthreads();
    if (g == 0 && jj < 16)
        *(float4*)(emb + (size_t)slot * 64 + jj * 4) =
            add4(comb1(pb, jj), *(const float4*)(o2b + jj * 4));
}

// one block per pair
__global__ __launch_bounds__(128) void k_pair(
    const float* __restrict__ emb,
    const float* __restrict__ WT_l1, const float* __restrict__ l1b,
    const float* __restrict__ WT_l2, const float* __restrict__ l2b,
    const float* __restrict__ l3W, const float* __restrict__ l3b,
    float* __restrict__ out) {
    __shared__ __align__(16) float pv[128], z1[128], z2s[64];
    __shared__ __align__(16) float4 pb[4 * 32];
    const int p = blockIdx.x, tid = threadIdx.x, g = tid >> 5, jj = tid & 31;
    pv[tid] = (tid < 64) ? emb[(size_t)(2 * p) * 64 + tid]
                         : emb[(size_t)(2 * p + 1) * 64 + (tid - 64)];
    __syncthreads();
    pb[g * 32 + jj] = mv_ks1(WT_l1, pv, g, jj);
    __syncthreads();
    if (g == 0)
        *(float4*)(z1 + jj * 4) = relu4(add4(comb1(pb, jj), *(const float4*)(l1b + jj * 4)));
    __syncthreads();
    pb[g * 32 + jj] = mv_ks1_64(WT_l2, z1, g, jj);
    __syncthreads();
    if (g == 0 && jj < 16)
        *(float4*)(z2s + jj * 4) = relu4(add4(comb1(pb, jj), *(const float4*)(l2b + jj * 4)));
    __syncthreads();
    if (tid < 64) {
        float v = z2s[tid] * l3W[tid];
        v += __shfl_xor(v, 1);
        v += __shfl_xor(v, 2);
        v += __shfl_xor(v, 4);
        v += __shfl_xor(v, 8);
        v += __shfl_xor(v, 16);
        v += __shfl_xor(v, 32);
        if (tid == 0) out[p] = 1.f / (1.f + __expf(-(v + l3b[0])));
    }
}

// ---------- launch ----------
extern "C" void kernel_launch(void* const* d_in, const int* in_sizes, int n_in,
                              void* d_out, int out_size, void* d_ws, size_t ws_size,
                              hipStream_t stream) {
    const float* nf  = (const float*)d_in[0];
    const int*   ei  = (const int*)d_in[1];
    const float* ts  = (const float*)d_in[2];
    const int*   tp  = (const int*)d_in[3];
    const float* inW = (const float*)d_in[4];
    const float* inb = (const float*)d_in[5];
    const float* teW1 = (const float*)d_in[6];
    const float* teb1 = (const float*)d_in[7];
    const float* teW2 = (const float*)d_in[8];
    const float* teb2 = (const float*)d_in[9];
    const float* aiW = (const float*)d_in[10];
    const float* aib = (const float*)d_in[11];
    const float* aoW = (const float*)d_in[12];
    const float* aob = (const float*)d_in[13];
    const float* ftW = (const float*)d_in[14];
    const float* ftb = (const float*)d_in[15];
    const float* opW = (const float*)d_in[16];
    const float* opb = (const float*)d_in[17];
    const float* o1W = (const float*)d_in[18];
    const float* o1b = (const float*)d_in[19];
    const float* o2W = (const float*)d_in[20];
    const float* o2b = (const float*)d_in[21];
    const float* l1W = (const float*)d_in[22];
    const float* l1b = (const float*)d_in[23];
    const float* l2W = (const float*)d_in[24];
    const float* l2b = (const float*)d_in[25];
    const float* l3W = (const float*)d_in[26];
    const float* l3b = (const float*)d_in[27];
    float* out = (float*)d_out;

    char* ws = (char*)d_ws;
    size_t off = 0;
    float* x    = (float*)(ws + off); off += (size_t)N_NODES * 128 * 4;       // 10.24 MB
    int*   cnt  = (int*)  (ws + off); off += N_SLOTS * 4;
    int2*  lst  = (int2*) (ws + off); off += (size_t)N_SLOTS * CAP * 8;
    float* tfu  = (float*)(ws + off); off += N_SLOTS * 128 * 4;
    float* emb  = (float*)(ws + off); off += N_SLOTS * 64 * 4;
    float* scb  = (float*)(ws + off); off += (size_t)N_SLOTS * CAP * 4 * 4;
    float* vbuf = (float*)(ws + off); off += (size_t)N_SLOTS * CAP * 128 * 4; // 8.4 MB
    float* WT   = (float*)(ws + off); off += (size_t)NMAT * MSTRIDE * 4;      // 1.2 MB

    k_prep_tr<<<N_SLOTS, 256, 0, stream>>>(ei, tp, inW, ftW, teW2, aiW, aoW, opW,
                                           o1W, o2W, l1W, l2W, WT, cnt, lst);

    for (int l = 0; l < 2; ++l) {
        const float* WT_ft = WT + (1 + l) * MSTRIDE;
        const float* WT_te2 = WT + (3 + l) * MSTRIDE;
        const float* WT_q = WT + (5 + 3 * l) * MSTRIDE;
        const float* WT_k = WT + (6 + 3 * l) * MSTRIDE;
        const float* WT_v = WT + (7 + 3 * l) * MSTRIDE;
        const float* WT_ao = WT + (11 + l) * MSTRIDE;
        const float* WT_op = WT + (13 + l) * MSTRIDE;
        const float* bq = aib + l * 384;
        k_edge<<<N_SLOTS, 256, 0, stream>>>(
            nf, x, ts, tp, cnt, lst,
            WT, inb, WT_ft, ftb + l * 128, teW1 + l * 128, teb1 + l * 128,
            WT_te2, teb2 + l * 128, WT_q, bq, WT_k, bq + 128, WT_v, bq + 256,
            x, tfu, scb, vbuf, l);
        k_reduce<<<N_SLOTS, 128, 0, stream>>>(
            cnt, tp, scb, vbuf, tfu, WT_ao, aob + l * 128,
            WT_op, opb + l * 128, x,
            WT + 15 * MSTRIDE, o1b, WT + 17 * MSTRIDE, o2b, emb, l);
    }
    k_pair<<<N_PAIRS, 128, 0, stream>>>(emb, WT + 16 * MSTRIDE, l1b,
                                        WT + 18 * MSTRIDE, l2b, l3W, l3b, out);
}

// Round 7
// 200.896 us; speedup vs baseline: 2.2543x; 1.0210x over previous
//
#include <hip/hip_runtime.h>
#include <math.h>

#define N_NODES 20000
#define N_EDGES 50000
#define N_SLOTS 256   // N_PAIRS * 2 flattened targets
#define N_PAIRS 128
#define CAP 64        // max incident edges per slot (deg ~ Poisson(5))
#define MSTRIDE 16384 // floats per transposed-matrix slot in ws
#define NMAT 19
#define TFLAG (1 << 30)

// ---------- helpers ----------
__device__ __forceinline__ float4 relu4(float4 v) {
    return make_float4(fmaxf(v.x, 0.f), fmaxf(v.y, 0.f), fmaxf(v.z, 0.f), fmaxf(v.w, 0.f));
}
__device__ __forceinline__ float4 add4(float4 a, float4 b) {
    return make_float4(a.x + b.x, a.y + b.y, a.z + b.z, a.w + b.w);
}
__device__ __forceinline__ void fma4(float4& acc, const float4 w, const float s) {
    acc.x = fmaf(w.x, s, acc.x); acc.y = fmaf(w.y, s, acc.y);
    acc.z = fmaf(w.z, s, acc.z); acc.w = fmaf(w.w, s, acc.w);
}
#define F4Z make_float4(0.f, 0.f, 0.f, 0.f)

// ===== 8-group K-split (256-thread blocks): group g covers k-chunks [4g,4g+4) =====
__device__ __forceinline__ float4 mv_ks1_g8(const float* __restrict__ WT,
                                            const float* __restrict__ xv128,
                                            int g, int jj) {
    const float4* W4 = (const float4*)WT;
    const float4* x4 = (const float4*)xv128;
    float4 acc = F4Z;
#pragma unroll
    for (int kk4 = 0; kk4 < 4; ++kk4) {
        int k4 = g * 4 + kk4;
        float4 xv = x4[k4];
        fma4(acc, W4[(k4 * 4 + 0) * 32 + jj], xv.x);
        fma4(acc, W4[(k4 * 4 + 1) * 32 + jj], xv.y);
        fma4(acc, W4[(k4 * 4 + 2) * 32 + jj], xv.z);
        fma4(acc, W4[(k4 * 4 + 3) * 32 + jj], xv.w);
    }
    return acc;
}
// 64-output variant (WT stored [128][64]); lanes jj>=16 compute duplicates
__device__ __forceinline__ float4 mv_ks1_g8_64(const float* __restrict__ WT,
                                               const float* __restrict__ xv128,
                                               int g, int jj) {
    const float4* W4 = (const float4*)WT;
    const float4* x4 = (const float4*)xv128;
    int j16 = jj & 15;
    float4 acc = F4Z;
#pragma unroll
    for (int kk4 = 0; kk4 < 4; ++kk4) {
        int k4 = g * 4 + kk4;
        float4 xv = x4[k4];
        fma4(acc, W4[(k4 * 4 + 0) * 16 + j16], xv.x);
        fma4(acc, W4[(k4 * 4 + 1) * 16 + j16], xv.y);
        fma4(acc, W4[(k4 * 4 + 2) * 16 + j16], xv.z);
        fma4(acc, W4[(k4 * 4 + 3) * 16 + j16], xv.w);
    }
    return acc;
}
__device__ __forceinline__ void mv8_g8(const float* __restrict__ WT,
                                       const float* __restrict__ xs,
                                       int g, int jj, float4* acc) {
    const float4* W4 = (const float4*)WT;
    const float4* x4 = (const float4*)xs;
#pragma unroll
    for (int kk4 = 0; kk4 < 4; ++kk4) {
        int k4 = g * 4 + kk4;
        float4 w0 = W4[(k4 * 4 + 0) * 32 + jj];
        float4 w1 = W4[(k4 * 4 + 1) * 32 + jj];
        float4 w2 = W4[(k4 * 4 + 2) * 32 + jj];
        float4 w3 = W4[(k4 * 4 + 3) * 32 + jj];
#pragma unroll
        for (int e = 0; e < 8; ++e) {
            float4 xv = x4[e * 32 + k4];
            fma4(acc[e], w0, xv.x); fma4(acc[e], w1, xv.y);
            fma4(acc[e], w2, xv.z); fma4(acc[e], w3, xv.w);
        }
    }
}
__device__ __forceinline__ float4 comb1_g8(const float4* pb, int jj) {
    float4 s = pb[jj];
#pragma unroll
    for (int gp = 1; gp < 8; ++gp) s = add4(s, pb[gp * 32 + jj]);
    return s;
}
__device__ __forceinline__ float4 comb8_g8(const float4* pb, int it, int jj) {
    float4 s = pb[it * 32 + jj];
#pragma unroll
    for (int gp = 1; gp < 8; ++gp) s = add4(s, pb[(gp * 8 + it) * 32 + jj]);
    return s;
}

// ===== 4-group variants for the 128-thread pair kernel =====
__device__ __forceinline__ float4 mv_ks1(const float* __restrict__ WT,
                                         const float* __restrict__ xv128,
                                         int g, int jj) {
    const float4* W4 = (const float4*)WT;
    const float4* x4 = (const float4*)xv128;
    float4 acc = F4Z;
#pragma unroll 2
    for (int kk4 = 0; kk4 < 8; ++kk4) {
        int k4 = g * 8 + kk4;
        float4 xv = x4[k4];
        fma4(acc, W4[(k4 * 4 + 0) * 32 + jj], xv.x);
        fma4(acc, W4[(k4 * 4 + 1) * 32 + jj], xv.y);
        fma4(acc, W4[(k4 * 4 + 2) * 32 + jj], xv.z);
        fma4(acc, W4[(k4 * 4 + 3) * 32 + jj], xv.w);
    }
    return acc;
}
__device__ __forceinline__ float4 mv_ks1_64(const float* __restrict__ WT,
                                            const float* __restrict__ xv128,
                                            int g, int jj) {
    const float4* W4 = (const float4*)WT;
    const float4* x4 = (const float4*)xv128;
    int j16 = jj & 15;
    float4 acc = F4Z;
#pragma unroll 2
    for (int kk4 = 0; kk4 < 8; ++kk4) {
        int k4 = g * 8 + kk4;
        float4 xv = x4[k4];
        fma4(acc, W4[(k4 * 4 + 0) * 16 + j16], xv.x);
        fma4(acc, W4[(k4 * 4 + 1) * 16 + j16], xv.y);
        fma4(acc, W4[(k4 * 4 + 2) * 16 + j16], xv.z);
        fma4(acc, W4[(k4 * 4 + 3) * 16 + j16], xv.w);
    }
    return acc;
}
__device__ __forceinline__ float4 comb1(const float4* pb, int jj) {
    return add4(add4(pb[jj], pb[32 + jj]), add4(pb[64 + jj], pb[96 + jj]));
}

// ---------- kernels ----------

// fused: weight transpose (blocks 0..71) + per-slot edge scan + target-flagging
__global__ __launch_bounds__(256) void k_prep_tr(
    const int* __restrict__ ei, const int* __restrict__ tp,
    const float* __restrict__ inW, const float* __restrict__ ftW,
    const float* __restrict__ teW2, const float* __restrict__ aiW,
    const float* __restrict__ aoW, const float* __restrict__ opW,
    const float* __restrict__ o1W, const float* __restrict__ o2W,
    const float* __restrict__ l1W, const float* __restrict__ l2W,
    float* __restrict__ WT, int* __restrict__ cnt, int2* __restrict__ lst) {
    __shared__ float tile[32][129];
    __shared__ int tps[N_SLOTS];
    __shared__ int lc;
    const int b = blockIdx.x;
    if (threadIdx.x == 0) lc = 0;
    if (b < 72) {  // block-uniform branch: barriers inside are legal
        int m, r0, rows;
        if (b < 68) { m = b >> 2; r0 = (b & 3) * 32; rows = 128; }
        else { int mm = b - 68; m = 17 + (mm >> 1); r0 = (mm & 1) * 32; rows = 64; }
        const float* src;
        if (m == 0) src = inW;
        else if (m <= 2) src = ftW + (m - 1) * MSTRIDE;
        else if (m <= 4) src = teW2 + (m - 3) * MSTRIDE;
        else if (m <= 10) src = aiW + (m - 5) * MSTRIDE;  // q0,k0,v0,q1,k1,v1
        else if (m <= 12) src = aoW + (m - 11) * MSTRIDE;
        else if (m <= 14) src = opW + (m - 13) * MSTRIDE;
        else if (m == 15) src = o1W;
        else if (m == 16) src = l1W;
        else if (m == 17) src = o2W;
        else src = l2W;
        float* dst = WT + m * MSTRIDE;
        for (int idx = threadIdx.x; idx < 32 * 128; idx += 256) {
            int r = idx >> 7, c = idx & 127;
            tile[r][c] = src[(r0 + r) * 128 + c];
        }
        __syncthreads();
        for (int idx = threadIdx.x; idx < 128 * 32; idx += 256) {
            int k = idx >> 5, jr = idx & 31;
            dst[k * rows + r0 + jr] = tile[jr][k];
        }
    }
    for (int i = threadIdx.x; i < N_SLOTS; i += 256) tps[i] = tp[i];
    __syncthreads();
    // per-slot incident-edge scan
    const int u = tps[b];
    const int4* src4 = (const int4*)ei;
    const int4* dst4 = (const int4*)(ei + N_EDGES);
    for (int e4 = threadIdx.x; e4 < N_EDGES / 4; e4 += 256) {
        int4 s = src4[e4];
        int4 d = dst4[e4];
        int ss[4] = {s.x, s.y, s.z, s.w};
        int dd[4] = {d.x, d.y, d.z, d.w};
#pragma unroll
        for (int t = 0; t < 4; ++t) {
            if (ss[t] == u || dd[t] == u) {
                int nbr = (ss[t] == u) ? dd[t] : ss[t];
                int pos = atomicAdd(&lc, 1);
                if (pos < CAP) lst[b * CAP + pos] = make_int2(e4 * 4 + t, nbr);
            }
        }
    }
    __syncthreads();
    if (threadIdx.x == 0) cnt[b] = lc;
    // flag entries whose neighbor is itself a target (race-avoidance in k_layer)
    int c = min(lc, CAP);
    if (threadIdx.x < c) {
        int2 en = lst[b * CAP + threadIdx.x];
        bool ist = false;
        for (int t = 0; t < N_SLOTS; ++t) ist |= (tps[t] == en.y);
        if (ist) { en.y |= TFLAG; lst[b * CAP + threadIdx.x] = en; }
    }
}

// one block (256 thr) per slot: phase A (x0_u, tf_u, q), phase B edge batches
// (scores/v in LDS), fused reduce: softmax + attn_out + op; layer 0 scatters
// relu(agg) into x; layer 1 runs the emb head -> emb[slot].
__global__ __launch_bounds__(256) void k_layer(
    const float* __restrict__ nf, const float* __restrict__ x,
    const float* __restrict__ ts, const int* __restrict__ tp,
    const int* __restrict__ cnt, const int2* __restrict__ lst,
    const float* __restrict__ WT_in, const float* __restrict__ inb,
    const float* __restrict__ WT_ft, const float* __restrict__ ftb,
    const float* __restrict__ teW1, const float* __restrict__ teb1,
    const float* __restrict__ WT_te2, const float* __restrict__ teb2,
    const float* __restrict__ WT_q, const float* __restrict__ bq,
    const float* __restrict__ WT_k, const float* __restrict__ bk,
    const float* __restrict__ WT_v, const float* __restrict__ bv,
    const float* __restrict__ WT_ao, const float* __restrict__ aob,
    const float* __restrict__ WT_op, const float* __restrict__ opb,
    const float* __restrict__ WT_o1, const float* __restrict__ o1b,
    const float* __restrict__ WT_o2, const float* __restrict__ o2b,
    float* __restrict__ x_out, float* __restrict__ emb, int layer) {
    __shared__ __align__(16) float xu[128], x0u[128], tfv[128], qv[128], sv[128];
    __shared__ __align__(16) float xs[8 * 128], t1s[8 * 128], x0s[8 * 128], zs[8 * 128];
    __shared__ __align__(16) float4 pb[8 * 8 * 32];   // 32 KB partials
    __shared__ __align__(16) float vbl[CAP * 128];    // 32 KB values
    __shared__ float scl[CAP * 4];
    __shared__ int nbr_s[8], tf_s[8];
    __shared__ float ts_s[8];
    const int slot = blockIdx.x, tid = threadIdx.x, g = tid >> 5, jj = tid & 31;
    const float scale = 0.17677669529663687f;  // 1/sqrt(32)
    const int u = tp[slot];
    const int c = min(cnt[slot], CAP);

    // ---- phase A ----
    if (tid < 128) xu[tid] = (layer == 0) ? nf[(size_t)u * 128 + tid]
                                          : x[(size_t)u * 128 + tid];
    __syncthreads();
    const float* xeff = xu;
    if (layer == 0) {
        pb[g * 32 + jj] = mv_ks1_g8(WT_in, xu, g, jj);
        __syncthreads();
        if (g == 0)
            *(float4*)(x0u + jj * 4) = add4(comb1_g8(pb, jj), *(const float4*)(inb + jj * 4));
        xeff = x0u;
        __syncthreads();
    }
    pb[g * 32 + jj] = mv_ks1_g8(WT_ft, xeff, g, jj);
    __syncthreads();
    if (g == 0)
        *(float4*)(tfv + jj * 4) = add4(comb1_g8(pb, jj), *(const float4*)(ftb + jj * 4));
    __syncthreads();
    pb[g * 32 + jj] = mv_ks1_g8(WT_q, tfv, g, jj);
    __syncthreads();
    if (g == 0)
        *(float4*)(qv + jj * 4) = add4(comb1_g8(pb, jj), *(const float4*)(bq + jj * 4));
    __syncthreads();

    // ---- phase B: edge batches of 8 (item it == group g) ----
    for (int base = 0; base < c; base += 8) {
        if (tid < 8) {
            int i = base + tid;
            int2 en = (i < c) ? lst[slot * CAP + i] : make_int2(0, 0);
            nbr_s[tid] = en.y & ~TFLAG;
            tf_s[tid] = (en.y & TFLAG) ? 1 : 0;
            ts_s[tid] = (i < c) ? ts[en.x] : 0.f;
        }
        __syncthreads();
        {   // stage neighbor row + time-encoding layer-1 activation
            int e = tid >> 5, c0 = jj * 4;
            const float* srcp = (layer == 0) ? (nf + (size_t)nbr_s[e] * 128 + c0)
                                             : (x + (size_t)nbr_s[e] * 128 + c0);
            float4 v = *(const float4*)srcp;
            float* dstp = (layer == 0) ? xs : x0s;
            *(float4*)(dstp + e * 128 + c0) = v;
            float tse = ts_s[e];
            float4 w = *(const float4*)(teW1 + c0);
            float4 b = *(const float4*)(teb1 + c0);
            *(float4*)(t1s + e * 128 + c0) =
                make_float4(fmaxf(fmaf(tse, w.x, b.x), 0.f),
                            fmaxf(fmaf(tse, w.y, b.y), 0.f),
                            fmaxf(fmaf(tse, w.z, b.z), 0.f),
                            fmaxf(fmaf(tse, w.w, b.w), 0.f));
        }
        __syncthreads();
        if (layer == 0) {  // x0_nbr = inW @ nf[nbr] + inb; persist relu(x0)
            float4 acc[8] = {F4Z, F4Z, F4Z, F4Z, F4Z, F4Z, F4Z, F4Z};
            mv8_g8(WT_in, xs, g, jj, acc);
#pragma unroll
            for (int e = 0; e < 8; ++e) pb[(g * 8 + e) * 32 + jj] = acc[e];
            __syncthreads();
            {
                float4 x0v = add4(comb8_g8(pb, g, jj), *(const float4*)(inb + jj * 4));
                *(float4*)(x0s + g * 128 + jj * 4) = x0v;
                // skip target rows: their final value is relu(agg), written by the
                // owning slot's fused reduce (same-kernel write race otherwise)
                if (base + g < c && !tf_s[g])
                    *(float4*)(x_out + (size_t)nbr_s[g] * 128 + jj * 4) = relu4(x0v);
            }
            __syncthreads();
        }
        {   // z = ftW@x0 + ftb + teW2@t1 + teb2
            float4 acc[8] = {F4Z, F4Z, F4Z, F4Z, F4Z, F4Z, F4Z, F4Z};
            mv8_g8(WT_ft, x0s, g, jj, acc);
#pragma unroll
            for (int e = 0; e < 8; ++e) pb[(g * 8 + e) * 32 + jj] = acc[e];
            __syncthreads();
            float4 za = comb8_g8(pb, g, jj);
            __syncthreads();
            float4 acc2[8] = {F4Z, F4Z, F4Z, F4Z, F4Z, F4Z, F4Z, F4Z};
            mv8_g8(WT_te2, t1s, g, jj, acc2);
#pragma unroll
            for (int e = 0; e < 8; ++e) pb[(g * 8 + e) * 32 + jj] = acc2[e];
            __syncthreads();
            float4 zb = comb8_g8(pb, g, jj);
            float4 z4 = add4(add4(za, zb),
                             add4(*(const float4*)(ftb + jj * 4),
                                  *(const float4*)(teb2 + jj * 4)));
            *(float4*)(zs + g * 128 + jj * 4) = z4;
            __syncthreads();
        }
        {   // k, v, score (v + scores stay in LDS)
            float4 acc[8] = {F4Z, F4Z, F4Z, F4Z, F4Z, F4Z, F4Z, F4Z};
            mv8_g8(WT_k, zs, g, jj, acc);
#pragma unroll
            for (int e = 0; e < 8; ++e) pb[(g * 8 + e) * 32 + jj] = acc[e];
            __syncthreads();
            float4 kk = add4(comb8_g8(pb, g, jj), *(const float4*)(bk + jj * 4));
            __syncthreads();
            float4 acc2[8] = {F4Z, F4Z, F4Z, F4Z, F4Z, F4Z, F4Z, F4Z};
            mv8_g8(WT_v, zs, g, jj, acc2);
#pragma unroll
            for (int e = 0; e < 8; ++e) pb[(g * 8 + e) * 32 + jj] = acc2[e];
            __syncthreads();
            float4 vv = add4(comb8_g8(pb, g, jj), *(const float4*)(bv + jj * 4));
            float4 q4 = *(const float4*)(qv + jj * 4);
            float pr = q4.x * kk.x + q4.y * kk.y + q4.z * kk.z + q4.w * kk.w;
            pr += __shfl_xor(pr, 1);
            pr += __shfl_xor(pr, 2);
            pr += __shfl_xor(pr, 4);  // sum over the 8 lanes of head jj>>3
            if (base + g < c) {
                if ((jj & 7) == 0) scl[(base + g) * 4 + (jj >> 3)] = pr * scale;
                *(float4*)(vbl + (base + g) * 128 + jj * 4) = vv;
            }
            __syncthreads();  // before next batch restages LDS
        }
    }

    // ---- fused reduce: softmax over LDS scores + weighted v-sum ----
    if (tid < 128) {
        int h = tid >> 5;
        if (c > 0) {
            float m = -INFINITY;
            for (int i = 0; i < c; ++i) m = fmaxf(m, scl[i * 4 + h]);
            float l = 0.f, o = 0.f;
            for (int i = 0; i < c; ++i) {
                float p = __expf(scl[i * 4 + h] - m);
                l += p;
                o = fmaf(p, vbl[i * 128 + tid], o);
            }
            sv[tid] = o / l;
        } else {
            sv[tid] = 0.f;
        }
    }
    __syncthreads();
    pb[g * 32 + jj] = mv_ks1_g8(WT_ao, sv, g, jj);
    __syncthreads();
    if (g == 0) {
        float4 z4;
        if (c > 0) z4 = add4(comb1_g8(pb, jj), *(const float4*)(aob + jj * 4));
        else z4 = *(const float4*)(tfv + jj * 4);
        *(float4*)(xu + jj * 4) = z4;  // reuse xu as z
    }
    __syncthreads();
    pb[g * 32 + jj] = mv_ks1_g8(WT_op, xu, g, jj);
    __syncthreads();
    if (layer == 0) {
        if (g == 0) {
            float4 a = relu4(add4(comb1_g8(pb, jj), *(const float4*)(opb + jj * 4)));
            *(float4*)(x_out + (size_t)u * 128 + jj * 4) = a;
        }
        return;
    }
    // layer 1: emb head
    if (g == 0)
        *(float4*)(x0u + jj * 4) =
            relu4(add4(comb1_g8(pb, jj), *(const float4*)(opb + jj * 4)));
    __syncthreads();
    pb[g * 32 + jj] = mv_ks1_g8(WT_o1, x0u, g, jj);
    __syncthreads();
    if (g == 0)
        *(float4*)(tfv + jj * 4) =
            relu4(add4(comb1_g8(pb, jj), *(const float4*)(o1b + jj * 4)));
    __syncthreads();
    pb[g * 32 + jj] = mv_ks1_g8_64(WT_o2, tfv, g, jj);
    __syncthreads();
    if (g == 0 && jj < 16)
        *(float4*)(emb + (size_t)slot * 64 + jj * 4) =
            add4(comb1_g8(pb, jj), *(const float4*)(o2b + jj * 4));
}

// one block per pair
__global__ __launch_bounds__(128) void k_pair(
    const float* __restrict__ emb,
    const float* __restrict__ WT_l1, const float* __restrict__ l1b,
    const float* __restrict__ WT_l2, const float* __restrict__ l2b,
    const float* __restrict__ l3W, const float* __restrict__ l3b,
    float* __restrict__ out) {
    __shared__ __align__(16) float pv[128], z1[128], z2s[64];
    __shared__ __align__(16) float4 pb[4 * 32];
    const int p = blockIdx.x, tid = threadIdx.x, g = tid >> 5, jj = tid & 31;
    pv[tid] = (tid < 64) ? emb[(size_t)(2 * p) * 64 + tid]
                         : emb[(size_t)(2 * p + 1) * 64 + (tid - 64)];
    __syncthreads();
    pb[g * 32 + jj] = mv_ks1(WT_l1, pv, g, jj);
    __syncthreads();
    if (g == 0)
        *(float4*)(z1 + jj * 4) = relu4(add4(comb1(pb, jj), *(const float4*)(l1b + jj * 4)));
    __syncthreads();
    pb[g * 32 + jj] = mv_ks1_64(WT_l2, z1, g, jj);
    __syncthreads();
    if (g == 0 && jj < 16)
        *(float4*)(z2s + jj * 4) = relu4(add4(comb1(pb, jj), *(const float4*)(l2b + jj * 4)));
    __syncthreads();
    if (tid < 64) {
        float v = z2s[tid] * l3W[tid];
        v += __shfl_xor(v, 1);
        v += __shfl_xor(v, 2);
        v += __shfl_xor(v, 4);
        v += __shfl_xor(v, 8);
        v += __shfl_xor(v, 16);
        v += __shfl_xor(v, 32);
        if (tid == 0) out[p] = 1.f / (1.f + __expf(-(v + l3b[0])));
    }
}

// ---------- launch ----------
extern "C" void kernel_launch(void* const* d_in, const int* in_sizes, int n_in,
                              void* d_out, int out_size, void* d_ws, size_t ws_size,
                              hipStream_t stream) {
    const float* nf  = (const float*)d_in[0];
    const int*   ei  = (const int*)d_in[1];
    const float* ts  = (const float*)d_in[2];
    const int*   tp  = (const int*)d_in[3];
    const float* inW = (const float*)d_in[4];
    const float* inb = (const float*)d_in[5];
    const float* teW1 = (const float*)d_in[6];
    const float* teb1 = (const float*)d_in[7];
    const float* teW2 = (const float*)d_in[8];
    const float* teb2 = (const float*)d_in[9];
    const float* aiW = (const float*)d_in[10];
    const float* aib = (const float*)d_in[11];
    const float* aoW = (const float*)d_in[12];
    const float* aob = (const float*)d_in[13];
    const float* ftW = (const float*)d_in[14];
    const float* ftb = (const float*)d_in[15];
    const float* opW = (const float*)d_in[16];
    const float* opb = (const float*)d_in[17];
    const float* o1W = (const float*)d_in[18];
    const float* o1b = (const float*)d_in[19];
    const float* o2W = (const float*)d_in[20];
    const float* o2b = (const float*)d_in[21];
    const float* l1W = (const float*)d_in[22];
    const float* l1b = (const float*)d_in[23];
    const float* l2W = (const float*)d_in[24];
    const float* l2b = (const float*)d_in[25];
    const float* l3W = (const float*)d_in[26];
    const float* l3b = (const float*)d_in[27];
    float* out = (float*)d_out;

    char* ws = (char*)d_ws;
    size_t off = 0;
    float* x    = (float*)(ws + off); off += (size_t)N_NODES * 128 * 4;   // 10.24 MB
    int*   cnt  = (int*)  (ws + off); off += N_SLOTS * 4;
    int2*  lst  = (int2*) (ws + off); off += (size_t)N_SLOTS * CAP * 8;
    float* emb  = (float*)(ws + off); off += N_SLOTS * 64 * 4;
    float* WT   = (float*)(ws + off); off += (size_t)NMAT * MSTRIDE * 4;  // 1.2 MB

    k_prep_tr<<<N_SLOTS, 256, 0, stream>>>(ei, tp, inW, ftW, teW2, aiW, aoW, opW,
                                           o1W, o2W, l1W, l2W, WT, cnt, lst);

    for (int l = 0; l < 2; ++l) {
        const float* WT_ft = WT + (1 + l) * MSTRIDE;
        const float* WT_te2 = WT + (3 + l) * MSTRIDE;
        const float* WT_q = WT + (5 + 3 * l) * MSTRIDE;
        const float* WT_k = WT + (6 + 3 * l) * MSTRIDE;
        const float* WT_v = WT + (7 + 3 * l) * MSTRIDE;
        const float* WT_ao = WT + (11 + l) * MSTRIDE;
        const float* WT_op = WT + (13 + l) * MSTRIDE;
        const float* bq = aib + l * 384;
        k_layer<<<N_SLOTS, 256, 0, stream>>>(
            nf, x, ts, tp, cnt, lst,
            WT, inb, WT_ft, ftb + l * 128, teW1 + l * 128, teb1 + l * 128,
            WT_te2, teb2 + l * 128, WT_q, bq, WT_k, bq + 128, WT_v, bq + 256,
            WT_ao, aob + l * 128, WT_op, opb + l * 128,
            WT + 15 * MSTRIDE, o1b, WT + 17 * MSTRIDE, o2b,
            x, emb, l);
    }
    k_pair<<<N_PAIRS, 128, 0, stream>>>(emb, WT + 16 * MSTRIDE, l1b,
                                        WT + 18 * MSTRIDE, l2b, l3W, l3b, out);
}